// Round 3
// baseline (1014.062 us; speedup 1.0000x reference)
//
#include <hip/hip_runtime.h>
#include <math.h>

namespace {

constexpr int kB  = 2;
constexpr int kS  = 2048;
constexpr int kD  = 512;
constexpr int kH  = 8;
constexpr int kDK = 64;
constexpr int kM  = kB * kS;   // 4096 rows
constexpr int kBH = kB * kH;   // 16

__device__ __forceinline__ float wave_sum64(float v) {
#pragma unroll
    for (int o = 32; o > 0; o >>= 1) v += __shfl_xor(v, o, 64);
    return v;
}

#define MAXN_F  ((float)(1.0 - 1e-5))
#define ACLIP_F ((float)(1.0 - 1e-7))

// ------------------- GEMM: Y(M x 512) = X(M x 512) @ W(512 x 512)^T -------------------
__global__ __launch_bounds__(256) void gemm_xwt(const float* __restrict__ X,
                                                const float* __restrict__ W,
                                                float* __restrict__ Y) {
    __shared__ float As[16][68];
    __shared__ float Bs[16][68];
    const int bm = blockIdx.x * 64;
    const int bn = blockIdx.y * 64;
    const int tid = threadIdx.x;
    const int ty = tid >> 4, tx = tid & 15;
    const int lr = tid >> 2;
    const int lc = (tid & 3) * 4;
    float acc[4][4] = {};
    for (int k0 = 0; k0 < 512; k0 += 16) {
        float4 av = *(const float4*)(X + (size_t)(bm + lr) * 512 + k0 + lc);
        float4 bv = *(const float4*)(W + (size_t)(bn + lr) * 512 + k0 + lc);
        As[lc + 0][lr] = av.x; As[lc + 1][lr] = av.y; As[lc + 2][lr] = av.z; As[lc + 3][lr] = av.w;
        Bs[lc + 0][lr] = bv.x; Bs[lc + 1][lr] = bv.y; Bs[lc + 2][lr] = bv.z; Bs[lc + 3][lr] = bv.w;
        __syncthreads();
#pragma unroll
        for (int k = 0; k < 16; ++k) {
            float4 a = *(const float4*)&As[k][ty * 4];
            float4 b = *(const float4*)&Bs[k][tx * 4];
            float ar[4] = {a.x, a.y, a.z, a.w};
            float br[4] = {b.x, b.y, b.z, b.w};
#pragma unroll
            for (int i = 0; i < 4; ++i)
#pragma unroll
                for (int j = 0; j < 4; ++j) acc[i][j] = fmaf(ar[i], br[j], acc[i][j]);
        }
        __syncthreads();
    }
#pragma unroll
    for (int i = 0; i < 4; ++i) {
        *(float4*)(Y + (size_t)(bm + ty * 4 + i) * 512 + bn + tx * 4) =
            make_float4(acc[i][0], acc[i][1], acc[i][2], acc[i][3]);
    }
}

// --------- mobius_linear tail: res=matvec scale; mobius_add(res,b); project ---------
__global__ __launch_bounds__(256) void rowops(const float* __restrict__ X,
                                              const float* __restrict__ MX,
                                              const float* __restrict__ bvec,
                                              float* __restrict__ out) {
    __shared__ float4 red4[4];
    __shared__ float red1[4];
    const int row = blockIdx.x;
    const int tid = threadIdx.x;
    const float2 xv = ((const float2*)(X + (size_t)row * kD))[tid];
    const float2 mv = ((const float2*)(MX + (size_t)row * kD))[tid];
    const float2 bv = ((const float2*)bvec)[tid];
    float sx  = fmaf(xv.x, xv.x, xv.y * xv.y);
    float sm  = fmaf(mv.x, mv.x, mv.y * mv.y);
    float smb = fmaf(mv.x, bv.x, mv.y * bv.y);
    float sb  = fmaf(bv.x, bv.x, bv.y * bv.y);
#pragma unroll
    for (int o = 32; o > 0; o >>= 1) {
        sx  += __shfl_xor(sx, o, 64);
        sm  += __shfl_xor(sm, o, 64);
        smb += __shfl_xor(smb, o, 64);
        sb  += __shfl_xor(sb, o, 64);
    }
    if ((tid & 63) == 0) red4[tid >> 6] = make_float4(sx, sm, smb, sb);
    __syncthreads();
    {
        float4 r0 = red4[0], r1 = red4[1], r2 = red4[2], r3 = red4[3];
        sx  = r0.x + r1.x + r2.x + r3.x;
        sm  = r0.y + r1.y + r2.y + r3.y;
        smb = r0.z + r1.z + r2.z + r3.z;
        sb  = r0.w + r1.w + r2.w + r3.w;
    }
    float xn  = sqrtf(fmaxf(sx, 1e-15f));
    float mxn = sqrtf(fmaxf(sm, 1e-15f));
    float xc  = fminf(xn, ACLIP_F);
    float at  = 0.5f * logf((1.f + xc) / (1.f - xc));       // artanh(xn)
    float sc  = tanhf(mxn / xn * at) / mxn;                 // res = sc * mx
    if (sm == 0.f) sc = 0.f;                                // all(mx==0) branch
    float x2 = sc * sc * sm;
    float xy = sc * smb;
    float y2 = sb;
    float c1 = 1.f + 2.f * xy + y2;
    float c2 = 1.f - x2;
    float den = fmaxf(1.f + 2.f * xy + x2 * y2, 1e-15f);
    float idn = 1.f / den;
    float ux = (c1 * sc * mv.x + c2 * bv.x) * idn;
    float uy = (c1 * sc * mv.y + c2 * bv.y) * idn;
    float su = wave_sum64(fmaf(ux, ux, uy * uy));
    if ((tid & 63) == 0) red1[tid >> 6] = su;
    __syncthreads();
    su = (red1[0] + red1[1]) + (red1[2] + red1[3]);
    float n = sqrtf(fmaxf(su, 1e-15f));
    float f = (n > MAXN_F) ? (MAXN_F / n) : 1.f;
    ((float2*)(out + (size_t)row * kD))[tid] = make_float2(ux * f, uy * f);
}

// ---- prep: per-head-row |q|^2, |k|^2 and LV = logmap0(V_head), bh-major layout ----
__global__ __launch_bounds__(256) void prep(const float* __restrict__ Qp,
                                            const float* __restrict__ Kp,
                                            const float* __restrict__ Vp,
                                            float* __restrict__ qn2,
                                            float* __restrict__ kn2,
                                            float* __restrict__ LV) {
    const int gid  = blockIdx.x * 4 + (threadIdx.x >> 6); // 0..32767 = bh*2048+s
    const int lane = threadIdx.x & 63;
    const int bh = gid >> 11, s = gid & 2047;
    const int b = bh >> 3, h = bh & 7;
    const size_t src = (size_t)(b * kS + s) * kD + h * kDK + lane;
    float q = Qp[src], k = Kp[src], v = Vp[src];
    float sq = wave_sum64(q * q);
    float sk = wave_sum64(k * k);
    float sv = wave_sum64(v * v);
    if (lane == 0) { qn2[gid] = sq; kn2[gid] = sk; }
    float yn = sqrtf(fmaxf(sv, 1e-15f));
    float yc = fminf(yn, ACLIP_F);
    float coef = 0.5f * logf((1.f + yc) / (1.f - yc)) / yn;
    LV[(size_t)gid * kDK + lane] = v * coef;
}

// ----- scores+exp: per (b,h) 128x128 tile of exp(-dist/8), plus per-row partial sums -----
__global__ __launch_bounds__(256) void scores_k(const float* __restrict__ Qp,
                                                const float* __restrict__ Kp,
                                                const float* __restrict__ qn2,
                                                const float* __restrict__ kn2,
                                                float* __restrict__ attn,
                                                float* __restrict__ part) {
    __shared__ float Qs[64][128];   // [d][m^swz]
    __shared__ float Ks[64][128];   // [d][n^swz]
    const int i0 = blockIdx.x * 128;
    const int j0 = blockIdx.y * 128;
    const int bh = blockIdx.z;
    const int b = bh >> 3, h = bh & 7;
    const int tid = threadIdx.x;
    for (int t = tid; t < 2048; t += 256) {
        const int r = t >> 4;
        const int c = (t & 15) * 4;
        const int mp = r ^ (c & 28);
        float4 qv = *(const float4*)(Qp + (size_t)(b * kS + i0 + r) * kD + h * kDK + c);
        float4 kv = *(const float4*)(Kp + (size_t)(b * kS + j0 + r) * kD + h * kDK + c);
        Qs[c + 0][mp] = qv.x; Qs[c + 1][mp] = qv.y; Qs[c + 2][mp] = qv.z; Qs[c + 3][mp] = qv.w;
        Ks[c + 0][mp] = kv.x; Ks[c + 1][mp] = kv.y; Ks[c + 2][mp] = kv.z; Ks[c + 3][mp] = kv.w;
    }
    __syncthreads();
    const int ty = tid >> 4, tx = tid & 15;
    float acc[8][8] = {};
#pragma unroll 8
    for (int d = 0; d < 64; ++d) {
        const int f = d & 28;
        float4 a0 = *(const float4*)&Qs[d][(ty * 4) ^ f];
        float4 a1 = *(const float4*)&Qs[d][64 + ((ty * 4) ^ f)];
        float4 b0 = *(const float4*)&Ks[d][(tx * 4) ^ f];
        float4 b1 = *(const float4*)&Ks[d][64 + ((tx * 4) ^ f)];
        float ar[8] = {a0.x, a0.y, a0.z, a0.w, a1.x, a1.y, a1.z, a1.w};
        float br[8] = {b0.x, b0.y, b0.z, b0.w, b1.x, b1.y, b1.z, b1.w};
#pragma unroll
        for (int i = 0; i < 8; ++i)
#pragma unroll
            for (int j = 0; j < 8; ++j) acc[i][j] = fmaf(ar[i], br[j], acc[i][j]);
    }
    float x2r[8], y2c[8];
#pragma unroll
    for (int i = 0; i < 8; ++i) {
        int ri = (i < 4) ? (ty * 4 + i) : (64 + ty * 4 + (i - 4));
        x2r[i] = qn2[(bh << 11) + i0 + ri];
    }
#pragma unroll
    for (int j = 0; j < 8; ++j) {
        int cj = (j < 4) ? (tx * 4 + j) : (64 + tx * 4 + (j - 4));
        y2c[j] = kn2[(bh << 11) + j0 + cj];
    }
#pragma unroll
    for (int i = 0; i < 8; ++i) {
        int ri = (i < 4) ? (ty * 4 + i) : (64 + ty * 4 + (i - 4));
        float* orow = attn + (size_t)((bh << 11) + i0 + ri) * kS + j0;
        float o[8];
        float rs = 0.f;
#pragma unroll
        for (int j = 0; j < 8; ++j) {
            float xy = acc[i][j];
            float x2 = x2r[i], y2 = y2c[j];
            float A  = 1.f - 2.f * xy + y2;
            float Bc = 1.f - x2;
            float num2 = A * A * x2 + Bc * Bc * y2 - 2.f * A * Bc * xy;
            float den  = fmaxf(1.f - 2.f * xy + x2 * y2, 1e-15f);
            float sn   = __builtin_amdgcn_sqrtf(fmaxf(num2, 0.f));
            float dm   = den - sn;
            dm = fmaxf(dm, (den + sn) * 5e-8f);               // == artanh clip at 1-1e-7
            float rr = (den + sn) * __builtin_amdgcn_rcpf(dm); // (1+t)/(1-t)
            float e = __builtin_amdgcn_exp2f(-0.125f * __builtin_amdgcn_logf(rr));
            o[j] = e;
            rs += e;
        }
        *(float4*)(orow + tx * 4)      = make_float4(o[0], o[1], o[2], o[3]);
        *(float4*)(orow + 64 + tx * 4) = make_float4(o[4], o[5], o[6], o[7]);
#pragma unroll
        for (int off = 8; off > 0; off >>= 1) rs += __shfl_xor(rs, off, 64);
        if (tx == 0) part[(size_t)((bh << 11) + i0 + ri) * 16 + blockIdx.y] = rs;
    }
}

// ------------------- invS1[row] = 1 / sum_j exp-partials -------------------
__global__ __launch_bounds__(256) void finalize_inv(const float* __restrict__ part,
                                                    float* __restrict__ invS1) {
    const int row = blockIdx.x * 256 + threadIdx.x;
    const float4* p = (const float4*)(part + (size_t)row * 16);
    float4 a = p[0], b = p[1], c = p[2], d = p[3];
    float s = ((a.x + a.y) + (a.z + a.w)) + ((b.x + b.y) + (b.z + b.w)) +
              ((c.x + c.y) + (c.z + c.w)) + ((d.x + d.y) + (d.z + d.w));
    invS1[row] = 1.f / s;
}

// ---- pv: normalize attn tile (write back final attn) + mid = attn @ LV, per (b,h) ----
// M=64 tile -> 512 blocks (2/CU), reg-staged double-buffered LDS, 4x4 microtile.
// Pad-68 rows: As[r][k..k+3] b128 over 4 rows hits 4 distinct bank-quads (17r+k/4 mod 8),
// Ls[k][4tx..] b128 over 16 tx is 2-way (free).
__global__ __launch_bounds__(256) void pv_k(float* __restrict__ attn,
                                            const float* __restrict__ LV,
                                            const float* __restrict__ invS1,
                                            float* __restrict__ mid) {
    __shared__ float As[2][64][68];  // [buf][m][k]
    __shared__ float Ls[2][64][68];  // [buf][k][n]
    __shared__ float isv[64];
    const int i0 = blockIdx.x * 64;
    const int bh = blockIdx.y;
    const int tid = threadIdx.x;
    const int ty = tid >> 4, tx = tid & 15;
    const int sr = tid >> 4;          // staging rows sr, sr+16, sr+32, sr+48
    const int sc = (tid & 15) * 4;    // staging cols
    const size_t arow = (size_t)((bh << 11) + i0);
    const size_t lrow = (size_t)(bh << 11);
    if (tid < 64) isv[tid] = invS1[arow + tid];

    float4 a_reg[4], l_reg[4];
#pragma unroll
    for (int q = 0; q < 4; ++q) {
        a_reg[q] = *(const float4*)(attn + (arow + sr + q * 16) * kS + sc);
        l_reg[q] = *(const float4*)(LV + (lrow + sr + q * 16) * kDK + sc);
    }
    __syncthreads();   // isv ready
#pragma unroll
    for (int q = 0; q < 4; ++q) {
        const int r = sr + q * 16;
        float is = isv[r];
        float4 av = a_reg[q];
        av.x *= is; av.y *= is; av.z *= is; av.w *= is;
        *(float4*)&As[0][r][sc] = av;
        *(float4*)(attn + (arow + r) * kS + sc) = av;   // final normalized attn
        *(float4*)&Ls[0][r][sc] = l_reg[q];
    }

    float acc[4][4] = {};
    for (int c = 0; c < 32; ++c) {
        const int cur = c & 1;
        __syncthreads();           // LDS[cur] fully written
        const int k1 = (c + 1) * 64;
        if (c < 31) {
#pragma unroll
            for (int q = 0; q < 4; ++q) {
                a_reg[q] = *(const float4*)(attn + (arow + sr + q * 16) * kS + k1 + sc);
                l_reg[q] = *(const float4*)(LV + (lrow + k1 + sr + q * 16) * kDK + sc);
            }
        }
#pragma unroll
        for (int kk = 0; kk < 64; kk += 4) {
            float4 l0 = *(const float4*)&Ls[cur][kk + 0][tx * 4];
            float4 l1 = *(const float4*)&Ls[cur][kk + 1][tx * 4];
            float4 l2 = *(const float4*)&Ls[cur][kk + 2][tx * 4];
            float4 l3 = *(const float4*)&Ls[cur][kk + 3][tx * 4];
#pragma unroll
            for (int i = 0; i < 4; ++i) {
                float4 ai = *(const float4*)&As[cur][ty * 4 + i][kk];
                acc[i][0] = fmaf(ai.x, l0.x, acc[i][0]);
                acc[i][1] = fmaf(ai.x, l0.y, acc[i][1]);
                acc[i][2] = fmaf(ai.x, l0.z, acc[i][2]);
                acc[i][3] = fmaf(ai.x, l0.w, acc[i][3]);
                acc[i][0] = fmaf(ai.y, l1.x, acc[i][0]);
                acc[i][1] = fmaf(ai.y, l1.y, acc[i][1]);
                acc[i][2] = fmaf(ai.y, l1.z, acc[i][2]);
                acc[i][3] = fmaf(ai.y, l1.w, acc[i][3]);
                acc[i][0] = fmaf(ai.z, l2.x, acc[i][0]);
                acc[i][1] = fmaf(ai.z, l2.y, acc[i][1]);
                acc[i][2] = fmaf(ai.z, l2.z, acc[i][2]);
                acc[i][3] = fmaf(ai.z, l2.w, acc[i][3]);
                acc[i][0] = fmaf(ai.w, l3.x, acc[i][0]);
                acc[i][1] = fmaf(ai.w, l3.y, acc[i][1]);
                acc[i][2] = fmaf(ai.w, l3.z, acc[i][2]);
                acc[i][3] = fmaf(ai.w, l3.w, acc[i][3]);
            }
        }
        if (c < 31) {
            const int nxt = cur ^ 1;
#pragma unroll
            for (int q = 0; q < 4; ++q) {
                const int r = sr + q * 16;
                float is = isv[r];
                float4 av = a_reg[q];
                av.x *= is; av.y *= is; av.z *= is; av.w *= is;
                *(float4*)&As[nxt][r][sc] = av;
                *(float4*)(attn + (arow + r) * kS + k1 + sc) = av;
                *(float4*)&Ls[nxt][r][sc] = l_reg[q];
            }
        }
    }
#pragma unroll
    for (int i = 0; i < 4; ++i) {
        *(float4*)(mid + (arow + ty * 4 + i) * kDK + tx * 4) =
            make_float4(acc[i][0], acc[i][1], acc[i][2], acc[i][3]);
    }
}

// ------------------- expmap0 + regather heads to (B,S,D) -------------------
__global__ __launch_bounds__(256) void expmap_gather(const float* __restrict__ mid,
                                                     float* __restrict__ outcat) {
    const int gid  = blockIdx.x * 4 + (threadIdx.x >> 6);
    const int lane = threadIdx.x & 63;
    const int bh = gid >> 11, s = gid & 2047;
    const int b = bh >> 3, h = bh & 7;
    float u = mid[(size_t)gid * kDK + lane];
    float sq = wave_sum64(u * u);
    float un = sqrtf(fmaxf(sq, 1e-15f));
    float coef = tanhf(un) / un;
    outcat[(size_t)(b * kS + s) * kD + h * kDK + lane] = u * coef;
}

} // namespace

extern "C" void kernel_launch(void* const* d_in, const int* in_sizes, int n_in,
                              void* d_out, int out_size, void* d_ws, size_t ws_size,
                              hipStream_t stream) {
    const float* q  = (const float*)d_in[0];
    const float* k  = (const float*)d_in[1];
    const float* v  = (const float*)d_in[2];
    const float* Wq = (const float*)d_in[3];
    const float* bq = (const float*)d_in[4];
    const float* Wk = (const float*)d_in[5];
    const float* bk = (const float*)d_in[6];
    const float* Wv = (const float*)d_in[7];
    const float* bv = (const float*)d_in[8];
    const float* Wo = (const float*)d_in[9];
    const float* bo = (const float*)d_in[10];

    float* out  = (float*)d_out;
    float* attn = out + (size_t)kM * kD;   // out (2M floats), then attn (64M floats)

    constexpr size_t NBUF = (size_t)kM * kD; // 2,097,152 floats
    float* ws  = (float*)d_ws;
    float* A0  = ws;              // Qp  -> later mid
    float* A1  = ws + NBUF;       // Kp  -> later outcat
    float* A2  = ws + 2 * NBUF;   // Vp  -> later part/invS1 -> later mx for final gemm
    float* A3  = ws + 3 * NBUF;   // mx scratch -> later LV
    float* qn2 = ws + 4 * NBUF;
    float* kn2 = qn2 + (size_t)kBH * kS;
    float* part  = A2;                              // 32768*16 floats (Vp dead by then)
    float* invS1 = A2 + (size_t)kBH * kS * 16;      // 32768 floats

    dim3 gg(kM / 64, kD / 64);

    gemm_xwt<<<gg, 256, 0, stream>>>(q, Wq, A3);
    rowops<<<kM, 256, 0, stream>>>(q, A3, bq, A0);
    gemm_xwt<<<gg, 256, 0, stream>>>(k, Wk, A3);
    rowops<<<kM, 256, 0, stream>>>(k, A3, bk, A1);
    gemm_xwt<<<gg, 256, 0, stream>>>(v, Wv, A3);
    rowops<<<kM, 256, 0, stream>>>(v, A3, bv, A2);

    prep<<<(kBH * kS) / 4, 256, 0, stream>>>(A0, A1, A2, qn2, kn2, A3);

    dim3 sg(kS / 128, kS / 128, kBH);
    scores_k<<<sg, 256, 0, stream>>>(A0, A1, qn2, kn2, attn, part);

    finalize_inv<<<(kBH * kS) / 256, 256, 0, stream>>>(part, invS1);

    dim3 pg(kS / 64, kBH);
    pv_k<<<pg, 256, 0, stream>>>(attn, A3, invS1, A0);

    expmap_gather<<<(kBH * kS) / 4, 256, 0, stream>>>(A0, A1);

    gemm_xwt<<<gg, 256, 0, stream>>>(A1, Wo, A2);
    rowops<<<kM, 256, 0, stream>>>(A1, A2, bo, out);
}

// Round 4
// 564.174 us; speedup vs baseline: 1.7974x; 1.7974x over previous
//
#include <hip/hip_runtime.h>
#include <math.h>

namespace {

constexpr int kB  = 2;
constexpr int kS  = 2048;
constexpr int kD  = 512;
constexpr int kH  = 8;
constexpr int kDK = 64;
constexpr int kM  = kB * kS;   // 4096 rows
constexpr int kBH = kB * kH;   // 16

__device__ __forceinline__ float wave_sum64(float v) {
#pragma unroll
    for (int o = 32; o > 0; o >>= 1) v += __shfl_xor(v, o, 64);
    return v;
}

#define MAXN_F  ((float)(1.0 - 1e-5))
#define ACLIP_F ((float)(1.0 - 1e-7))

// ------------------- GEMM: Y(M x 512) = X(M x 512) @ W(512 x 512)^T -------------------
__global__ __launch_bounds__(256) void gemm_xwt(const float* __restrict__ X,
                                                const float* __restrict__ W,
                                                float* __restrict__ Y) {
    __shared__ float As[16][68];
    __shared__ float Bs[16][68];
    const int bm = blockIdx.x * 64;
    const int bn = blockIdx.y * 64;
    const int tid = threadIdx.x;
    const int ty = tid >> 4, tx = tid & 15;
    const int lr = tid >> 2;
    const int lc = (tid & 3) * 4;
    float acc[4][4] = {};
    for (int k0 = 0; k0 < 512; k0 += 16) {
        float4 av = *(const float4*)(X + (size_t)(bm + lr) * 512 + k0 + lc);
        float4 bv = *(const float4*)(W + (size_t)(bn + lr) * 512 + k0 + lc);
        As[lc + 0][lr] = av.x; As[lc + 1][lr] = av.y; As[lc + 2][lr] = av.z; As[lc + 3][lr] = av.w;
        Bs[lc + 0][lr] = bv.x; Bs[lc + 1][lr] = bv.y; Bs[lc + 2][lr] = bv.z; Bs[lc + 3][lr] = bv.w;
        __syncthreads();
#pragma unroll
        for (int k = 0; k < 16; ++k) {
            float4 a = *(const float4*)&As[k][ty * 4];
            float4 b = *(const float4*)&Bs[k][tx * 4];
            float ar[4] = {a.x, a.y, a.z, a.w};
            float br[4] = {b.x, b.y, b.z, b.w};
#pragma unroll
            for (int i = 0; i < 4; ++i)
#pragma unroll
                for (int j = 0; j < 4; ++j) acc[i][j] = fmaf(ar[i], br[j], acc[i][j]);
        }
        __syncthreads();
    }
#pragma unroll
    for (int i = 0; i < 4; ++i) {
        *(float4*)(Y + (size_t)(bm + ty * 4 + i) * 512 + bn + tx * 4) =
            make_float4(acc[i][0], acc[i][1], acc[i][2], acc[i][3]);
    }
}

// --------- mobius_linear tail: res=matvec scale; mobius_add(res,b); project ---------
__global__ __launch_bounds__(256) void rowops(const float* __restrict__ X,
                                              const float* __restrict__ MX,
                                              const float* __restrict__ bvec,
                                              float* __restrict__ out) {
    __shared__ float4 red4[4];
    __shared__ float red1[4];
    const int row = blockIdx.x;
    const int tid = threadIdx.x;
    const float2 xv = ((const float2*)(X + (size_t)row * kD))[tid];
    const float2 mv = ((const float2*)(MX + (size_t)row * kD))[tid];
    const float2 bv = ((const float2*)bvec)[tid];
    float sx  = fmaf(xv.x, xv.x, xv.y * xv.y);
    float sm  = fmaf(mv.x, mv.x, mv.y * mv.y);
    float smb = fmaf(mv.x, bv.x, mv.y * bv.y);
    float sb  = fmaf(bv.x, bv.x, bv.y * bv.y);
#pragma unroll
    for (int o = 32; o > 0; o >>= 1) {
        sx  += __shfl_xor(sx, o, 64);
        sm  += __shfl_xor(sm, o, 64);
        smb += __shfl_xor(smb, o, 64);
        sb  += __shfl_xor(sb, o, 64);
    }
    if ((tid & 63) == 0) red4[tid >> 6] = make_float4(sx, sm, smb, sb);
    __syncthreads();
    {
        float4 r0 = red4[0], r1 = red4[1], r2 = red4[2], r3 = red4[3];
        sx  = r0.x + r1.x + r2.x + r3.x;
        sm  = r0.y + r1.y + r2.y + r3.y;
        smb = r0.z + r1.z + r2.z + r3.z;
        sb  = r0.w + r1.w + r2.w + r3.w;
    }
    float xn  = sqrtf(fmaxf(sx, 1e-15f));
    float mxn = sqrtf(fmaxf(sm, 1e-15f));
    float xc  = fminf(xn, ACLIP_F);
    float at  = 0.5f * logf((1.f + xc) / (1.f - xc));       // artanh(xn)
    float sc  = tanhf(mxn / xn * at) / mxn;                 // res = sc * mx
    if (sm == 0.f) sc = 0.f;                                // all(mx==0) branch
    float x2 = sc * sc * sm;
    float xy = sc * smb;
    float y2 = sb;
    float c1 = 1.f + 2.f * xy + y2;
    float c2 = 1.f - x2;
    float den = fmaxf(1.f + 2.f * xy + x2 * y2, 1e-15f);
    float idn = 1.f / den;
    float ux = (c1 * sc * mv.x + c2 * bv.x) * idn;
    float uy = (c1 * sc * mv.y + c2 * bv.y) * idn;
    float su = wave_sum64(fmaf(ux, ux, uy * uy));
    if ((tid & 63) == 0) red1[tid >> 6] = su;
    __syncthreads();
    su = (red1[0] + red1[1]) + (red1[2] + red1[3]);
    float n = sqrtf(fmaxf(su, 1e-15f));
    float f = (n > MAXN_F) ? (MAXN_F / n) : 1.f;
    ((float2*)(out + (size_t)row * kD))[tid] = make_float2(ux * f, uy * f);
}

// ---- prep: per-head-row |q|^2, |k|^2 and LV = logmap0(V_head), bh-major layout ----
__global__ __launch_bounds__(256) void prep(const float* __restrict__ Qp,
                                            const float* __restrict__ Kp,
                                            const float* __restrict__ Vp,
                                            float* __restrict__ qn2,
                                            float* __restrict__ kn2,
                                            float* __restrict__ LV) {
    const int gid  = blockIdx.x * 4 + (threadIdx.x >> 6); // 0..32767 = bh*2048+s
    const int lane = threadIdx.x & 63;
    const int bh = gid >> 11, s = gid & 2047;
    const int b = bh >> 3, h = bh & 7;
    const size_t src = (size_t)(b * kS + s) * kD + h * kDK + lane;
    float q = Qp[src], k = Kp[src], v = Vp[src];
    float sq = wave_sum64(q * q);
    float sk = wave_sum64(k * k);
    float sv = wave_sum64(v * v);
    if (lane == 0) { qn2[gid] = sq; kn2[gid] = sk; }
    float yn = sqrtf(fmaxf(sv, 1e-15f));
    float yc = fminf(yn, ACLIP_F);
    float coef = 0.5f * logf((1.f + yc) / (1.f - yc)) / yn;
    LV[(size_t)gid * kDK + lane] = v * coef;
}

// ----- scores+exp: per (b,h) 128x128 tile of exp(-dist/8), plus per-row partial sums -----
__global__ __launch_bounds__(256) void scores_k(const float* __restrict__ Qp,
                                                const float* __restrict__ Kp,
                                                const float* __restrict__ qn2,
                                                const float* __restrict__ kn2,
                                                float* __restrict__ attn,
                                                float* __restrict__ part) {
    __shared__ float Qs[64][128];   // [d][m^swz]
    __shared__ float Ks[64][128];   // [d][n^swz]
    const int i0 = blockIdx.x * 128;
    const int j0 = blockIdx.y * 128;
    const int bh = blockIdx.z;
    const int b = bh >> 3, h = bh & 7;
    const int tid = threadIdx.x;
    for (int t = tid; t < 2048; t += 256) {
        const int r = t >> 4;
        const int c = (t & 15) * 4;
        const int mp = r ^ (c & 28);
        float4 qv = *(const float4*)(Qp + (size_t)(b * kS + i0 + r) * kD + h * kDK + c);
        float4 kv = *(const float4*)(Kp + (size_t)(b * kS + j0 + r) * kD + h * kDK + c);
        Qs[c + 0][mp] = qv.x; Qs[c + 1][mp] = qv.y; Qs[c + 2][mp] = qv.z; Qs[c + 3][mp] = qv.w;
        Ks[c + 0][mp] = kv.x; Ks[c + 1][mp] = kv.y; Ks[c + 2][mp] = kv.z; Ks[c + 3][mp] = kv.w;
    }
    __syncthreads();
    const int ty = tid >> 4, tx = tid & 15;
    float acc[8][8] = {};
#pragma unroll 8
    for (int d = 0; d < 64; ++d) {
        const int f = d & 28;
        float4 a0 = *(const float4*)&Qs[d][(ty * 4) ^ f];
        float4 a1 = *(const float4*)&Qs[d][64 + ((ty * 4) ^ f)];
        float4 b0 = *(const float4*)&Ks[d][(tx * 4) ^ f];
        float4 b1 = *(const float4*)&Ks[d][64 + ((tx * 4) ^ f)];
        float ar[8] = {a0.x, a0.y, a0.z, a0.w, a1.x, a1.y, a1.z, a1.w};
        float br[8] = {b0.x, b0.y, b0.z, b0.w, b1.x, b1.y, b1.z, b1.w};
#pragma unroll
        for (int i = 0; i < 8; ++i)
#pragma unroll
            for (int j = 0; j < 8; ++j) acc[i][j] = fmaf(ar[i], br[j], acc[i][j]);
    }
    float x2r[8], y2c[8];
#pragma unroll
    for (int i = 0; i < 8; ++i) {
        int ri = (i < 4) ? (ty * 4 + i) : (64 + ty * 4 + (i - 4));
        x2r[i] = qn2[(bh << 11) + i0 + ri];
    }
#pragma unroll
    for (int j = 0; j < 8; ++j) {
        int cj = (j < 4) ? (tx * 4 + j) : (64 + tx * 4 + (j - 4));
        y2c[j] = kn2[(bh << 11) + j0 + cj];
    }
#pragma unroll
    for (int i = 0; i < 8; ++i) {
        int ri = (i < 4) ? (ty * 4 + i) : (64 + ty * 4 + (i - 4));
        float* orow = attn + (size_t)((bh << 11) + i0 + ri) * kS + j0;
        float o[8];
        float rs = 0.f;
#pragma unroll
        for (int j = 0; j < 8; ++j) {
            float xy = acc[i][j];
            float x2 = x2r[i], y2 = y2c[j];
            float A  = 1.f - 2.f * xy + y2;
            float Bc = 1.f - x2;
            float num2 = A * A * x2 + Bc * Bc * y2 - 2.f * A * Bc * xy;
            float den  = fmaxf(1.f - 2.f * xy + x2 * y2, 1e-15f);
            float sn   = __builtin_amdgcn_sqrtf(fmaxf(num2, 0.f));
            float dm   = den - sn;
            dm = fmaxf(dm, (den + sn) * 5e-8f);               // == artanh clip at 1-1e-7
            float rr = (den + sn) * __builtin_amdgcn_rcpf(dm); // (1+t)/(1-t)
            float e = __builtin_amdgcn_exp2f(-0.125f * __builtin_amdgcn_logf(rr));
            o[j] = e;
            rs += e;
        }
        *(float4*)(orow + tx * 4)      = make_float4(o[0], o[1], o[2], o[3]);
        *(float4*)(orow + 64 + tx * 4) = make_float4(o[4], o[5], o[6], o[7]);
#pragma unroll
        for (int off = 8; off > 0; off >>= 1) rs += __shfl_xor(rs, off, 64);
        if (tx == 0) part[(size_t)((bh << 11) + i0 + ri) * 16 + blockIdx.y] = rs;
    }
}

// ------------------- invS1[row] = 1 / sum_j exp-partials -------------------
__global__ __launch_bounds__(256) void finalize_inv(const float* __restrict__ part,
                                                    float* __restrict__ invS1) {
    const int row = blockIdx.x * 256 + threadIdx.x;
    const float4* p = (const float4*)(part + (size_t)row * 16);
    float4 a = p[0], b = p[1], c = p[2], d = p[3];
    float s = ((a.x + a.y) + (a.z + a.w)) + ((b.x + b.y) + (b.z + b.w)) +
              ((c.x + c.y) + (c.z + c.w)) + ((d.x + d.y) + (d.z + d.w));
    invS1[row] = 1.f / s;
}

// ---- pv: normalize attn (write back) + partial mid over a 1024-wide k-range ----
// M=64 tile, K-split 2 via blockIdx.z -> 1024 blocks, ~34 KB LDS -> 4 blocks/CU.
// Single-buffer LDS (round-2 proven structure: 84 VGPR, 0 conflicts), TLP hides latency.
__global__ __launch_bounds__(256) void pv_k(float* __restrict__ attn,
                                            const float* __restrict__ LV,
                                            const float* __restrict__ invS1,
                                            float* __restrict__ mid0,
                                            float* __restrict__ mid1) {
    __shared__ float As[64][64];   // [k][m ^ (k&28)]
    __shared__ float Ls[64][68];   // [k][n]
    __shared__ float isv[64];
    const int i0 = blockIdx.x * 64;
    const int bh = blockIdx.y;
    const int kz = blockIdx.z;
    const int tid = threadIdx.x;
    const int ty = tid >> 4, tx = tid & 15;
    const size_t arow = (size_t)((bh << 11) + i0);
    const size_t lrow = (size_t)(bh << 11);
    if (tid < 64) isv[tid] = invS1[arow + tid];
    __syncthreads();

    float acc[4][4] = {};
    for (int c = 0; c < 16; ++c) {
        const int k0 = kz * 1024 + c * 64;
        for (int t = tid; t < 1024; t += 256) {
            const int r = t >> 4;          // attn row within tile
            const int cc = (t & 15) * 4;   // k within chunk
            float* ap = attn + (arow + r) * kS + k0 + cc;
            float4 av = *(const float4*)ap;
            float is = isv[r];
            av.x *= is; av.y *= is; av.z *= is; av.w *= is;
            const int mp = r ^ (cc & 28);
            As[cc + 0][mp] = av.x; As[cc + 1][mp] = av.y;
            As[cc + 2][mp] = av.z; As[cc + 3][mp] = av.w;
            *(float4*)ap = av;             // final normalized attn
        }
        for (int t = tid; t < 1024; t += 256) {
            const int r = t >> 4;          // LV row within chunk
            const int cc = (t & 15) * 4;   // n
            *(float4*)&Ls[r][cc] = *(const float4*)(LV + (lrow + k0 + r) * kDK + cc);
        }
        __syncthreads();
#pragma unroll 8
        for (int k = 0; k < 64; ++k) {
            const int f = k & 28;
            float4 a = *(const float4*)&As[k][(ty * 4) ^ f];
            float4 bb = *(const float4*)&Ls[k][tx * 4];
            float ar[4] = {a.x, a.y, a.z, a.w};
            float br[4] = {bb.x, bb.y, bb.z, bb.w};
#pragma unroll
            for (int i = 0; i < 4; ++i)
#pragma unroll
                for (int j = 0; j < 4; ++j) acc[i][j] = fmaf(ar[i], br[j], acc[i][j]);
        }
        __syncthreads();
    }
    float* mp = kz ? mid1 : mid0;
#pragma unroll
    for (int i = 0; i < 4; ++i) {
        *(float4*)(mp + (arow + ty * 4 + i) * kDK + tx * 4) =
            make_float4(acc[i][0], acc[i][1], acc[i][2], acc[i][3]);
    }
}

// ------------- expmap0 (sum of 2 mid partials) + regather heads to (B,S,D) -------------
__global__ __launch_bounds__(256) void expmap_gather(const float* __restrict__ mid0,
                                                     const float* __restrict__ mid1,
                                                     float* __restrict__ outcat) {
    const int gid  = blockIdx.x * 4 + (threadIdx.x >> 6);
    const int lane = threadIdx.x & 63;
    const int bh = gid >> 11, s = gid & 2047;
    const int b = bh >> 3, h = bh & 7;
    const size_t idx = (size_t)gid * kDK + lane;
    float u = mid0[idx] + mid1[idx];
    float sq = wave_sum64(u * u);
    float un = sqrtf(fmaxf(sq, 1e-15f));
    float coef = tanhf(un) / un;
    outcat[(size_t)(b * kS + s) * kD + h * kDK + lane] = u * coef;
}

} // namespace

extern "C" void kernel_launch(void* const* d_in, const int* in_sizes, int n_in,
                              void* d_out, int out_size, void* d_ws, size_t ws_size,
                              hipStream_t stream) {
    const float* q  = (const float*)d_in[0];
    const float* k  = (const float*)d_in[1];
    const float* v  = (const float*)d_in[2];
    const float* Wq = (const float*)d_in[3];
    const float* bq = (const float*)d_in[4];
    const float* Wk = (const float*)d_in[5];
    const float* bk = (const float*)d_in[6];
    const float* Wv = (const float*)d_in[7];
    const float* bv = (const float*)d_in[8];
    const float* Wo = (const float*)d_in[9];
    const float* bo = (const float*)d_in[10];

    float* out  = (float*)d_out;
    float* attn = out + (size_t)kM * kD;   // out (2M floats), then attn (64M floats)

    constexpr size_t NBUF = (size_t)kM * kD; // 2,097,152 floats
    float* ws  = (float*)d_ws;
    float* A0  = ws;              // Qp  -> later mid partial 0
    float* A1  = ws + NBUF;       // Kp  -> later outcat
    float* A2  = ws + 2 * NBUF;   // Vp  -> later part/invS1 -> later mx for final gemm
    float* A3  = ws + 3 * NBUF;   // mx scratch -> later LV
    float* qn2 = ws + 4 * NBUF;
    float* kn2 = qn2 + (size_t)kBH * kS;
    float* part  = A2;                              // 32768*16 floats (Vp dead by then)
    float* invS1 = A2 + (size_t)kBH * kS * 16;      // 32768 floats
    float* mid0  = A0;                              // Qp dead after scores_k
    float* mid1  = out;                             // out region free until final rowops

    dim3 gg(kM / 64, kD / 64);

    gemm_xwt<<<gg, 256, 0, stream>>>(q, Wq, A3);
    rowops<<<kM, 256, 0, stream>>>(q, A3, bq, A0);
    gemm_xwt<<<gg, 256, 0, stream>>>(k, Wk, A3);
    rowops<<<kM, 256, 0, stream>>>(k, A3, bk, A1);
    gemm_xwt<<<gg, 256, 0, stream>>>(v, Wv, A3);
    rowops<<<kM, 256, 0, stream>>>(v, A3, bv, A2);

    prep<<<(kBH * kS) / 4, 256, 0, stream>>>(A0, A1, A2, qn2, kn2, A3);

    dim3 sg(kS / 128, kS / 128, kBH);
    scores_k<<<sg, 256, 0, stream>>>(A0, A1, qn2, kn2, attn, part);

    finalize_inv<<<(kBH * kS) / 256, 256, 0, stream>>>(part, invS1);

    dim3 pg(kS / 64, kBH, 2);
    pv_k<<<pg, 256, 0, stream>>>(attn, A3, invS1, mid0, mid1);

    expmap_gather<<<(kBH * kS) / 4, 256, 0, stream>>>(mid0, mid1, A1);

    gemm_xwt<<<gg, 256, 0, stream>>>(A1, Wo, A2);
    rowops<<<kM, 256, 0, stream>>>(A1, A2, bo, out);
}

// Round 5
// 530.712 us; speedup vs baseline: 1.9108x; 1.0631x over previous
//
#include <hip/hip_runtime.h>
#include <math.h>

namespace {

constexpr int kB  = 2;
constexpr int kS  = 2048;
constexpr int kD  = 512;
constexpr int kH  = 8;
constexpr int kDK = 64;
constexpr int kM  = kB * kS;   // 4096 rows
constexpr int kBH = kB * kH;   // 16

typedef __attribute__((ext_vector_type(8))) short bf16x8;
typedef __attribute__((ext_vector_type(4))) float f32x4;

__device__ __forceinline__ float wave_sum64(float v) {
#pragma unroll
    for (int o = 32; o > 0; o >>= 1) v += __shfl_xor(v, o, 64);
    return v;
}

__device__ __forceinline__ unsigned short f2bf(float f) {
    unsigned u = __float_as_uint(f);
    unsigned r = (u + 0x7FFF + ((u >> 16) & 1)) >> 16;   // round-to-nearest-even
    return (unsigned short)r;
}

#define MAXN_F  ((float)(1.0 - 1e-5))
#define ACLIP_F ((float)(1.0 - 1e-7))

// ------------------- GEMM: Y(M x 512) = X(M x 512) @ W(512 x 512)^T -------------------
__global__ __launch_bounds__(256) void gemm_xwt(const float* __restrict__ X,
                                                const float* __restrict__ W,
                                                float* __restrict__ Y) {
    __shared__ float As[16][68];
    __shared__ float Bs[16][68];
    const int bm = blockIdx.x * 64;
    const int bn = blockIdx.y * 64;
    const int tid = threadIdx.x;
    const int ty = tid >> 4, tx = tid & 15;
    const int lr = tid >> 2;
    const int lc = (tid & 3) * 4;
    float acc[4][4] = {};
    for (int k0 = 0; k0 < 512; k0 += 16) {
        float4 av = *(const float4*)(X + (size_t)(bm + lr) * 512 + k0 + lc);
        float4 bv = *(const float4*)(W + (size_t)(bn + lr) * 512 + k0 + lc);
        As[lc + 0][lr] = av.x; As[lc + 1][lr] = av.y; As[lc + 2][lr] = av.z; As[lc + 3][lr] = av.w;
        Bs[lc + 0][lr] = bv.x; Bs[lc + 1][lr] = bv.y; Bs[lc + 2][lr] = bv.z; Bs[lc + 3][lr] = bv.w;
        __syncthreads();
#pragma unroll
        for (int k = 0; k < 16; ++k) {
            float4 a = *(const float4*)&As[k][ty * 4];
            float4 b = *(const float4*)&Bs[k][tx * 4];
            float ar[4] = {a.x, a.y, a.z, a.w};
            float br[4] = {b.x, b.y, b.z, b.w};
#pragma unroll
            for (int i = 0; i < 4; ++i)
#pragma unroll
                for (int j = 0; j < 4; ++j) acc[i][j] = fmaf(ar[i], br[j], acc[i][j]);
        }
        __syncthreads();
    }
#pragma unroll
    for (int i = 0; i < 4; ++i) {
        *(float4*)(Y + (size_t)(bm + ty * 4 + i) * 512 + bn + tx * 4) =
            make_float4(acc[i][0], acc[i][1], acc[i][2], acc[i][3]);
    }
}

// --------- mobius_linear tail: res=matvec scale; mobius_add(res,b); project ---------
__global__ __launch_bounds__(256) void rowops(const float* __restrict__ X,
                                              const float* __restrict__ MX,
                                              const float* __restrict__ bvec,
                                              float* __restrict__ out) {
    __shared__ float4 red4[4];
    __shared__ float red1[4];
    const int row = blockIdx.x;
    const int tid = threadIdx.x;
    const float2 xv = ((const float2*)(X + (size_t)row * kD))[tid];
    const float2 mv = ((const float2*)(MX + (size_t)row * kD))[tid];
    const float2 bv = ((const float2*)bvec)[tid];
    float sx  = fmaf(xv.x, xv.x, xv.y * xv.y);
    float sm  = fmaf(mv.x, mv.x, mv.y * mv.y);
    float smb = fmaf(mv.x, bv.x, mv.y * bv.y);
    float sb  = fmaf(bv.x, bv.x, bv.y * bv.y);
#pragma unroll
    for (int o = 32; o > 0; o >>= 1) {
        sx  += __shfl_xor(sx, o, 64);
        sm  += __shfl_xor(sm, o, 64);
        smb += __shfl_xor(smb, o, 64);
        sb  += __shfl_xor(sb, o, 64);
    }
    if ((tid & 63) == 0) red4[tid >> 6] = make_float4(sx, sm, smb, sb);
    __syncthreads();
    {
        float4 r0 = red4[0], r1 = red4[1], r2 = red4[2], r3 = red4[3];
        sx  = r0.x + r1.x + r2.x + r3.x;
        sm  = r0.y + r1.y + r2.y + r3.y;
        smb = r0.z + r1.z + r2.z + r3.z;
        sb  = r0.w + r1.w + r2.w + r3.w;
    }
    float xn  = sqrtf(fmaxf(sx, 1e-15f));
    float mxn = sqrtf(fmaxf(sm, 1e-15f));
    float xc  = fminf(xn, ACLIP_F);
    float at  = 0.5f * logf((1.f + xc) / (1.f - xc));       // artanh(xn)
    float sc  = tanhf(mxn / xn * at) / mxn;                 // res = sc * mx
    if (sm == 0.f) sc = 0.f;                                // all(mx==0) branch
    float x2 = sc * sc * sm;
    float xy = sc * smb;
    float y2 = sb;
    float c1 = 1.f + 2.f * xy + y2;
    float c2 = 1.f - x2;
    float den = fmaxf(1.f + 2.f * xy + x2 * y2, 1e-15f);
    float idn = 1.f / den;
    float ux = (c1 * sc * mv.x + c2 * bv.x) * idn;
    float uy = (c1 * sc * mv.y + c2 * bv.y) * idn;
    float su = wave_sum64(fmaf(ux, ux, uy * uy));
    if ((tid & 63) == 0) red1[tid >> 6] = su;
    __syncthreads();
    su = (red1[0] + red1[1]) + (red1[2] + red1[3]);
    float n = sqrtf(fmaxf(su, 1e-15f));
    float f = (n > MAXN_F) ? (MAXN_F / n) : 1.f;
    ((float2*)(out + (size_t)row * kD))[tid] = make_float2(ux * f, uy * f);
}

// ---- prep2: per-head-row |q|^2,|k|^2 + LVbT[bh][n][k] = bf16(logmap0(V_head))^T ----
// One block per (bh, 64-wide k-tile); LDS transpose so LVbT writes are k-contiguous.
__global__ __launch_bounds__(256) void prep2(const float* __restrict__ Qp,
                                             const float* __restrict__ Kp,
                                             const float* __restrict__ Vp,
                                             float* __restrict__ qn2,
                                             float* __restrict__ kn2,
                                             unsigned short* __restrict__ LVbT) {
    __shared__ unsigned short T[64][66];   // [n][s_local], 66 -> 2-way banks (free)
    const int bh = blockIdx.x >> 5;
    const int k0 = (blockIdx.x & 31) * 64;
    const int b = bh >> 3, h = bh & 7;
    const int w = threadIdx.x >> 6, l = threadIdx.x & 63;
#pragma unroll 4
    for (int i = 0; i < 16; ++i) {
        const int s = k0 + w * 16 + i;
        const size_t src = (size_t)(b * kS + s) * kD + h * kDK + l;
        float qv = Qp[src], kv = Kp[src], vv = Vp[src];
        float sq = wave_sum64(qv * qv);
        float sk = wave_sum64(kv * kv);
        float sv = wave_sum64(vv * vv);
        if (l == 0) { qn2[(bh << 11) + s] = sq; kn2[(bh << 11) + s] = sk; }
        float yn = sqrtf(fmaxf(sv, 1e-15f));
        float yc = fminf(yn, ACLIP_F);
        float coef = 0.5f * logf((1.f + yc) / (1.f - yc)) / yn;
        T[l][w * 16 + i] = f2bf(vv * coef);
    }
    __syncthreads();
    const int n = threadIdx.x >> 2, kk = (threadIdx.x & 3) * 16;
    const unsigned int* Tr = (const unsigned int*)&T[n][kk];
    unsigned int u0 = Tr[0], u1 = Tr[1], u2 = Tr[2], u3 = Tr[3];
    unsigned int u4 = Tr[4], u5 = Tr[5], u6 = Tr[6], u7 = Tr[7];
    unsigned short* dst = LVbT + (((size_t)(bh * 64 + n)) << 11) + k0 + kk;
    *(uint4*)dst = make_uint4(u0, u1, u2, u3);
    *(uint4*)(dst + 8) = make_uint4(u4, u5, u6, u7);
}

// ----- scores+exp: per (b,h) 128x128 tile of exp(-dist/8), plus per-row partial sums -----
__global__ __launch_bounds__(256) void scores_k(const float* __restrict__ Qp,
                                                const float* __restrict__ Kp,
                                                const float* __restrict__ qn2,
                                                const float* __restrict__ kn2,
                                                float* __restrict__ attn,
                                                float* __restrict__ part) {
    __shared__ float Qs[64][128];   // [d][m^swz]
    __shared__ float Ks[64][128];   // [d][n^swz]
    const int i0 = blockIdx.x * 128;
    const int j0 = blockIdx.y * 128;
    const int bh = blockIdx.z;
    const int b = bh >> 3, h = bh & 7;
    const int tid = threadIdx.x;
    for (int t = tid; t < 2048; t += 256) {
        const int r = t >> 4;
        const int c = (t & 15) * 4;
        const int mp = r ^ (c & 28);
        float4 qv = *(const float4*)(Qp + (size_t)(b * kS + i0 + r) * kD + h * kDK + c);
        float4 kv = *(const float4*)(Kp + (size_t)(b * kS + j0 + r) * kD + h * kDK + c);
        Qs[c + 0][mp] = qv.x; Qs[c + 1][mp] = qv.y; Qs[c + 2][mp] = qv.z; Qs[c + 3][mp] = qv.w;
        Ks[c + 0][mp] = kv.x; Ks[c + 1][mp] = kv.y; Ks[c + 2][mp] = kv.z; Ks[c + 3][mp] = kv.w;
    }
    __syncthreads();
    const int ty = tid >> 4, tx = tid & 15;
    float acc[8][8] = {};
#pragma unroll 8
    for (int d = 0; d < 64; ++d) {
        const int f = d & 28;
        float4 a0 = *(const float4*)&Qs[d][(ty * 4) ^ f];
        float4 a1 = *(const float4*)&Qs[d][64 + ((ty * 4) ^ f)];
        float4 b0 = *(const float4*)&Ks[d][(tx * 4) ^ f];
        float4 b1 = *(const float4*)&Ks[d][64 + ((tx * 4) ^ f)];
        float ar[8] = {a0.x, a0.y, a0.z, a0.w, a1.x, a1.y, a1.z, a1.w};
        float br[8] = {b0.x, b0.y, b0.z, b0.w, b1.x, b1.y, b1.z, b1.w};
#pragma unroll
        for (int i = 0; i < 8; ++i)
#pragma unroll
            for (int j = 0; j < 8; ++j) acc[i][j] = fmaf(ar[i], br[j], acc[i][j]);
    }
    float x2r[8], y2c[8];
#pragma unroll
    for (int i = 0; i < 8; ++i) {
        int ri = (i < 4) ? (ty * 4 + i) : (64 + ty * 4 + (i - 4));
        x2r[i] = qn2[(bh << 11) + i0 + ri];
    }
#pragma unroll
    for (int j = 0; j < 8; ++j) {
        int cj = (j < 4) ? (tx * 4 + j) : (64 + tx * 4 + (j - 4));
        y2c[j] = kn2[(bh << 11) + j0 + cj];
    }
#pragma unroll
    for (int i = 0; i < 8; ++i) {
        int ri = (i < 4) ? (ty * 4 + i) : (64 + ty * 4 + (i - 4));
        float* orow = attn + (size_t)((bh << 11) + i0 + ri) * kS + j0;
        float o[8];
        float rs = 0.f;
#pragma unroll
        for (int j = 0; j < 8; ++j) {
            float xy = acc[i][j];
            float x2 = x2r[i], y2 = y2c[j];
            float A  = 1.f - 2.f * xy + y2;
            float Bc = 1.f - x2;
            float num2 = A * A * x2 + Bc * Bc * y2 - 2.f * A * Bc * xy;
            float den  = fmaxf(1.f - 2.f * xy + x2 * y2, 1e-15f);
            float sn   = __builtin_amdgcn_sqrtf(fmaxf(num2, 0.f));
            float dm   = den - sn;
            dm = fmaxf(dm, (den + sn) * 5e-8f);               // == artanh clip at 1-1e-7
            float rr = (den + sn) * __builtin_amdgcn_rcpf(dm); // (1+t)/(1-t)
            float e = __builtin_amdgcn_exp2f(-0.125f * __builtin_amdgcn_logf(rr));
            o[j] = e;
            rs += e;
        }
        *(float4*)(orow + tx * 4)      = make_float4(o[0], o[1], o[2], o[3]);
        *(float4*)(orow + 64 + tx * 4) = make_float4(o[4], o[5], o[6], o[7]);
#pragma unroll
        for (int off = 8; off > 0; off >>= 1) rs += __shfl_xor(rs, off, 64);
        if (tx == 0) part[(size_t)((bh << 11) + i0 + ri) * 16 + blockIdx.y] = rs;
    }
}

// ------------------- invS1[row] = 1 / sum_j exp-partials -------------------
__global__ __launch_bounds__(256) void finalize_inv(const float* __restrict__ part,
                                                    float* __restrict__ invS1) {
    const int row = blockIdx.x * 256 + threadIdx.x;
    const float4* p = (const float4*)(part + (size_t)row * 16);
    float4 a = p[0], b = p[1], c = p[2], d = p[3];
    float s = ((a.x + a.y) + (a.z + a.w)) + ((b.x + b.y) + (b.z + b.w)) +
              ((c.x + c.y) + (c.z + c.w)) + ((d.x + d.y) + (d.z + d.w));
    invS1[row] = 1.f / s;
}

// ---- pv_mfma: normalize attn (fp32 writeback) + mid partial = w @ LV via bf16 MFMA ----
// M=128 tile, K-split 2 -> 512 blocks. LDS kb-XOR swizzle: slot = kb ^ (row&7) on
// 16B granules -> both staging writes and fragment b128 reads land 2-way (free).
__global__ __launch_bounds__(256) void pv_mfma(float* __restrict__ attn,
                                               const unsigned short* __restrict__ LVbT,
                                               const float* __restrict__ invS1,
                                               float* __restrict__ mid0,
                                               float* __restrict__ mid1) {
    __shared__ unsigned short Ash[128 * 64];  // [row][k] bf16, swizzled
    __shared__ unsigned short Bsh[64 * 64];   // [col][k] bf16, swizzled
    __shared__ float isv[128];
    const int i0 = blockIdx.x * 128;
    const int bh = blockIdx.y;
    const int kz = blockIdx.z;
    const int tid = threadIdx.x;
    const int w = tid >> 6, l = tid & 63;
    const int lr = l & 15, lh = l >> 4;
    const size_t arow = (size_t)(bh << 11) + i0;
    const size_t lvbase = ((size_t)bh << 17);          // bh*64*2048
    if (tid < 128) isv[tid] = invS1[arow + tid];
    __syncthreads();

    f32x4 acc[2][4];
#pragma unroll
    for (int i = 0; i < 2; ++i)
#pragma unroll
        for (int j = 0; j < 4; ++j) acc[i][j] = (f32x4){0.f, 0.f, 0.f, 0.f};

    for (int c = 0; c < 16; ++c) {
        const int k0 = kz * 1024 + c * 64;
        // --- stage A: 128x64 fp32 attn -> normalize -> writeback -> bf16 LDS ---
#pragma unroll
        for (int it = 0; it < 8; ++it) {
            const int t = it * 256 + tid;
            const int r = t >> 4;
            const int c4 = (t & 15) * 4;
            float* ap = attn + (arow + r) * kS + k0 + c4;
            float4 av = *(const float4*)ap;
            const float is = isv[r];
            av.x *= is; av.y *= is; av.z *= is; av.w *= is;
            *(float4*)ap = av;                            // final normalized attn (fp32)
            const int slot = (c4 >> 3) ^ (r & 7);
            uint2 pk;
            pk.x = (unsigned)f2bf(av.x) | ((unsigned)f2bf(av.y) << 16);
            pk.y = (unsigned)f2bf(av.z) | ((unsigned)f2bf(av.w) << 16);
            *(uint2*)&Ash[r * 64 + slot * 8 + (c4 & 4)] = pk;
        }
        // --- stage B: 64x64 bf16 from LVbT (k-contiguous) ---
        {
            const int n = tid >> 2;
            const int kk = (tid & 3) * 16;
            const unsigned short* src = LVbT + lvbase + ((size_t)n << 11) + k0 + kk;
            uint4 s0 = *(const uint4*)src;
            uint4 s1 = *(const uint4*)(src + 8);
            const int kb = kk >> 3;
            *(uint4*)&Bsh[n * 64 + ((kb + 0) ^ (n & 7)) * 8] = s0;
            *(uint4*)&Bsh[n * 64 + ((kb + 1) ^ (n & 7)) * 8] = s1;
        }
        __syncthreads();
        // --- MFMA: wave w owns rows [w*32, w*32+32), all 64 cols ---
        const int wbase = w * 32;
#pragma unroll
        for (int ks = 0; ks < 2; ++ks) {
            const int kbase = ks * 4 + lh;
            bf16x8 afr[2], bfr[4];
#pragma unroll
            for (int fm = 0; fm < 2; ++fm) {
                const int row = wbase + fm * 16 + lr;
                afr[fm] = *(const bf16x8*)&Ash[row * 64 + (kbase ^ (row & 7)) * 8];
            }
#pragma unroll
            for (int fn = 0; fn < 4; ++fn) {
                const int col = fn * 16 + lr;
                bfr[fn] = *(const bf16x8*)&Bsh[col * 64 + (kbase ^ (col & 7)) * 8];
            }
#pragma unroll
            for (int fm = 0; fm < 2; ++fm)
#pragma unroll
                for (int fn = 0; fn < 4; ++fn)
                    acc[fm][fn] = __builtin_amdgcn_mfma_f32_16x16x32_bf16(
                        afr[fm], bfr[fn], acc[fm][fn], 0, 0, 0);
        }
        __syncthreads();
    }
    // C/D layout (m89-verified): col = lane&15, row = (lane>>4)*4 + reg
    float* mp = kz ? mid1 : mid0;
#pragma unroll
    for (int fm = 0; fm < 2; ++fm)
#pragma unroll
        for (int fn = 0; fn < 4; ++fn)
#pragma unroll
            for (int r = 0; r < 4; ++r) {
                const int row = (w * 32) + fm * 16 + lh * 4 + r;
                const int col = fn * 16 + lr;
                mp[(arow + row) * kDK + col] = acc[fm][fn][r];
            }
}

// ------------- expmap0 (sum of 2 mid partials) + regather heads to (B,S,D) -------------
__global__ __launch_bounds__(256) void expmap_gather(const float* __restrict__ mid0,
                                                     const float* __restrict__ mid1,
                                                     float* __restrict__ outcat) {
    const int gid  = blockIdx.x * 4 + (threadIdx.x >> 6);
    const int lane = threadIdx.x & 63;
    const int bh = gid >> 11, s = gid & 2047;
    const int b = bh >> 3, h = bh & 7;
    const size_t idx = (size_t)gid * kDK + lane;
    float u = mid0[idx] + mid1[idx];
    float sq = wave_sum64(u * u);
    float un = sqrtf(fmaxf(sq, 1e-15f));
    float coef = tanhf(un) / un;
    outcat[(size_t)(b * kS + s) * kD + h * kDK + lane] = u * coef;
}

} // namespace

extern "C" void kernel_launch(void* const* d_in, const int* in_sizes, int n_in,
                              void* d_out, int out_size, void* d_ws, size_t ws_size,
                              hipStream_t stream) {
    const float* q  = (const float*)d_in[0];
    const float* k  = (const float*)d_in[1];
    const float* v  = (const float*)d_in[2];
    const float* Wq = (const float*)d_in[3];
    const float* bq = (const float*)d_in[4];
    const float* Wk = (const float*)d_in[5];
    const float* bk = (const float*)d_in[6];
    const float* Wv = (const float*)d_in[7];
    const float* bv = (const float*)d_in[8];
    const float* Wo = (const float*)d_in[9];
    const float* bo = (const float*)d_in[10];

    float* out  = (float*)d_out;
    float* attn = out + (size_t)kM * kD;   // out (2M floats), then attn (64M floats)

    constexpr size_t NBUF = (size_t)kM * kD; // 2,097,152 floats
    float* ws  = (float*)d_ws;
    float* A0  = ws;              // Qp  -> later mid partial 0
    float* A1  = ws + NBUF;       // Kp  -> later outcat
    float* A2  = ws + 2 * NBUF;   // Vp  -> later part/invS1 -> later mx for final gemm
    float* A3  = ws + 3 * NBUF;   // mx scratch -> later LVbT (bf16, 4 MB of 8 MB)
    float* qn2 = ws + 4 * NBUF;
    float* kn2 = qn2 + (size_t)kBH * kS;
    float* part  = A2;                              // 32768*16 floats (Vp dead by then)
    float* invS1 = A2 + (size_t)kBH * kS * 16;      // 32768 floats
    float* mid0  = A0;                              // Qp dead after scores_k
    float* mid1  = out;                             // out region free until final rowops
    unsigned short* LVbT = (unsigned short*)A3;     // [bh][64][2048] bf16

    dim3 gg(kM / 64, kD / 64);

    gemm_xwt<<<gg, 256, 0, stream>>>(q, Wq, A3);
    rowops<<<kM, 256, 0, stream>>>(q, A3, bq, A0);
    gemm_xwt<<<gg, 256, 0, stream>>>(k, Wk, A3);
    rowops<<<kM, 256, 0, stream>>>(k, A3, bk, A1);
    gemm_xwt<<<gg, 256, 0, stream>>>(v, Wv, A3);
    rowops<<<kM, 256, 0, stream>>>(v, A3, bv, A2);

    prep2<<<kBH * 32, 256, 0, stream>>>(A0, A1, A2, qn2, kn2, LVbT);

    dim3 sg(kS / 128, kS / 128, kBH);
    scores_k<<<sg, 256, 0, stream>>>(A0, A1, qn2, kn2, attn, part);

    finalize_inv<<<(kBH * kS) / 256, 256, 0, stream>>>(part, invS1);

    dim3 pg(kS / 128, kBH, 2);
    pv_mfma<<<pg, 256, 0, stream>>>(attn, LVbT, invS1, mid0, mid1);

    expmap_gather<<<(kBH * kS) / 4, 256, 0, stream>>>(mid0, mid1, A1);

    gemm_xwt<<<gg, 256, 0, stream>>>(A1, Wo, A2);
    rowops<<<kM, 256, 0, stream>>>(A1, A2, bo, out);
}

// Round 6
// 492.022 us; speedup vs baseline: 2.0610x; 1.0786x over previous
//
#include <hip/hip_runtime.h>
#include <math.h>

namespace {

constexpr int kB  = 2;
constexpr int kS  = 2048;
constexpr int kD  = 512;
constexpr int kH  = 8;
constexpr int kDK = 64;
constexpr int kM  = kB * kS;   // 4096 rows
constexpr int kBH = kB * kH;   // 16

typedef __attribute__((ext_vector_type(8))) short bf16x8;
typedef __attribute__((ext_vector_type(4))) float f32x4;

__device__ __forceinline__ float wave_sum64(float v) {
#pragma unroll
    for (int o = 32; o > 0; o >>= 1) v += __shfl_xor(v, o, 64);
    return v;
}

__device__ __forceinline__ unsigned short f2bf(float f) {
    unsigned u = __float_as_uint(f);
    unsigned r = (u + 0x7FFF + ((u >> 16) & 1)) >> 16;   // round-to-nearest-even
    return (unsigned short)r;
}
__device__ __forceinline__ float bf2f(unsigned short h) {
    return __uint_as_float(((unsigned)h) << 16);
}

#define MAXN_F  ((float)(1.0 - 1e-5))
#define ACLIP_F ((float)(1.0 - 1e-7))

// ------------------- GEMM: Y(M x 512) = X(M x 512) @ W(512 x 512)^T -------------------
__global__ __launch_bounds__(256) void gemm_xwt(const float* __restrict__ X,
                                                const float* __restrict__ W,
                                                float* __restrict__ Y) {
    __shared__ float As[16][68];
    __shared__ float Bs[16][68];
    const int bm = blockIdx.x * 64;
    const int bn = blockIdx.y * 64;
    const int tid = threadIdx.x;
    const int ty = tid >> 4, tx = tid & 15;
    const int lr = tid >> 2;
    const int lc = (tid & 3) * 4;
    float acc[4][4] = {};
    for (int k0 = 0; k0 < 512; k0 += 16) {
        float4 av = *(const float4*)(X + (size_t)(bm + lr) * 512 + k0 + lc);
        float4 bv = *(const float4*)(W + (size_t)(bn + lr) * 512 + k0 + lc);
        As[lc + 0][lr] = av.x; As[lc + 1][lr] = av.y; As[lc + 2][lr] = av.z; As[lc + 3][lr] = av.w;
        Bs[lc + 0][lr] = bv.x; Bs[lc + 1][lr] = bv.y; Bs[lc + 2][lr] = bv.z; Bs[lc + 3][lr] = bv.w;
        __syncthreads();
#pragma unroll
        for (int k = 0; k < 16; ++k) {
            float4 a = *(const float4*)&As[k][ty * 4];
            float4 b = *(const float4*)&Bs[k][tx * 4];
            float ar[4] = {a.x, a.y, a.z, a.w};
            float br[4] = {b.x, b.y, b.z, b.w};
#pragma unroll
            for (int i = 0; i < 4; ++i)
#pragma unroll
                for (int j = 0; j < 4; ++j) acc[i][j] = fmaf(ar[i], br[j], acc[i][j]);
        }
        __syncthreads();
    }
#pragma unroll
    for (int i = 0; i < 4; ++i) {
        *(float4*)(Y + (size_t)(bm + ty * 4 + i) * 512 + bn + tx * 4) =
            make_float4(acc[i][0], acc[i][1], acc[i][2], acc[i][3]);
    }
}

// --------- mobius_linear tail: res=matvec scale; mobius_add(res,b); project ---------
__global__ __launch_bounds__(256) void rowops(const float* __restrict__ X,
                                              const float* __restrict__ MX,
                                              const float* __restrict__ bvec,
                                              float* __restrict__ out) {
    __shared__ float4 red4[4];
    __shared__ float red1[4];
    const int row = blockIdx.x;
    const int tid = threadIdx.x;
    const float2 xv = ((const float2*)(X + (size_t)row * kD))[tid];
    const float2 mv = ((const float2*)(MX + (size_t)row * kD))[tid];
    const float2 bv = ((const float2*)bvec)[tid];
    float sx  = fmaf(xv.x, xv.x, xv.y * xv.y);
    float sm  = fmaf(mv.x, mv.x, mv.y * mv.y);
    float smb = fmaf(mv.x, bv.x, mv.y * bv.y);
    float sb  = fmaf(bv.x, bv.x, bv.y * bv.y);
#pragma unroll
    for (int o = 32; o > 0; o >>= 1) {
        sx  += __shfl_xor(sx, o, 64);
        sm  += __shfl_xor(sm, o, 64);
        smb += __shfl_xor(smb, o, 64);
        sb  += __shfl_xor(sb, o, 64);
    }
    if ((tid & 63) == 0) red4[tid >> 6] = make_float4(sx, sm, smb, sb);
    __syncthreads();
    {
        float4 r0 = red4[0], r1 = red4[1], r2 = red4[2], r3 = red4[3];
        sx  = r0.x + r1.x + r2.x + r3.x;
        sm  = r0.y + r1.y + r2.y + r3.y;
        smb = r0.z + r1.z + r2.z + r3.z;
        sb  = r0.w + r1.w + r2.w + r3.w;
    }
    float xn  = sqrtf(fmaxf(sx, 1e-15f));
    float mxn = sqrtf(fmaxf(sm, 1e-15f));
    float xc  = fminf(xn, ACLIP_F);
    float at  = 0.5f * logf((1.f + xc) / (1.f - xc));       // artanh(xn)
    float sc  = tanhf(mxn / xn * at) / mxn;                 // res = sc * mx
    if (sm == 0.f) sc = 0.f;                                // all(mx==0) branch
    float x2 = sc * sc * sm;
    float xy = sc * smb;
    float y2 = sb;
    float c1 = 1.f + 2.f * xy + y2;
    float c2 = 1.f - x2;
    float den = fmaxf(1.f + 2.f * xy + x2 * y2, 1e-15f);
    float idn = 1.f / den;
    float ux = (c1 * sc * mv.x + c2 * bv.x) * idn;
    float uy = (c1 * sc * mv.y + c2 * bv.y) * idn;
    float su = wave_sum64(fmaf(ux, ux, uy * uy));
    if ((tid & 63) == 0) red1[tid >> 6] = su;
    __syncthreads();
    su = (red1[0] + red1[1]) + (red1[2] + red1[3]);
    float n = sqrtf(fmaxf(su, 1e-15f));
    float f = (n > MAXN_F) ? (MAXN_F / n) : 1.f;
    ((float2*)(out + (size_t)row * kD))[tid] = make_float2(ux * f, uy * f);
}

// ---- prep2: per-head-row |q|^2,|k|^2 + LVbT[bh][n][k] = bf16(logmap0(V_head))^T ----
__global__ __launch_bounds__(256) void prep2(const float* __restrict__ Qp,
                                             const float* __restrict__ Kp,
                                             const float* __restrict__ Vp,
                                             float* __restrict__ qn2,
                                             float* __restrict__ kn2,
                                             unsigned short* __restrict__ LVbT) {
    __shared__ unsigned short T[64][66];   // [n][s_local], 66 -> 2-way banks (free)
    const int bh = blockIdx.x >> 5;
    const int k0 = (blockIdx.x & 31) * 64;
    const int b = bh >> 3, h = bh & 7;
    const int w = threadIdx.x >> 6, l = threadIdx.x & 63;
#pragma unroll 4
    for (int i = 0; i < 16; ++i) {
        const int s = k0 + w * 16 + i;
        const size_t src = (size_t)(b * kS + s) * kD + h * kDK + l;
        float qv = Qp[src], kv = Kp[src], vv = Vp[src];
        float sq = wave_sum64(qv * qv);
        float sk = wave_sum64(kv * kv);
        float sv = wave_sum64(vv * vv);
        if (l == 0) { qn2[(bh << 11) + s] = sq; kn2[(bh << 11) + s] = sk; }
        float yn = sqrtf(fmaxf(sv, 1e-15f));
        float yc = fminf(yn, ACLIP_F);
        float coef = 0.5f * logf((1.f + yc) / (1.f - yc)) / yn;
        T[l][w * 16 + i] = f2bf(vv * coef);
    }
    __syncthreads();
    const int n = threadIdx.x >> 2, kk = (threadIdx.x & 3) * 16;
    const unsigned int* Tr = (const unsigned int*)&T[n][kk];
    unsigned int u0 = Tr[0], u1 = Tr[1], u2 = Tr[2], u3 = Tr[3];
    unsigned int u4 = Tr[4], u5 = Tr[5], u6 = Tr[6], u7 = Tr[7];
    unsigned short* dst = LVbT + (((size_t)(bh * 64 + n)) << 11) + k0 + kk;
    *(uint4*)dst = make_uint4(u0, u1, u2, u3);
    *(uint4*)(dst + 8) = make_uint4(u4, u5, u6, u7);
}

// ---- split_qk: Q,K head-gathered -> hi/lo bf16 planes [bh][s][64] (split-precision) ----
__global__ __launch_bounds__(256) void split_qk(const float* __restrict__ Qp,
                                                const float* __restrict__ Kp,
                                                unsigned short* __restrict__ Qhi,
                                                unsigned short* __restrict__ Qlo,
                                                unsigned short* __restrict__ Khi,
                                                unsigned short* __restrict__ Klo) {
    const int gid  = blockIdx.x * 4 + (threadIdx.x >> 6);
    const int lane = threadIdx.x & 63;
    const int bh = gid >> 11, s = gid & 2047;
    const int b = bh >> 3, h = bh & 7;
    const size_t src = (size_t)(b * kS + s) * kD + h * kDK + lane;
    const size_t dst = ((size_t)gid << 6) + lane;
    float qv = Qp[src];
    unsigned short qh = f2bf(qv);
    Qhi[dst] = qh;
    Qlo[dst] = f2bf(qv - bf2f(qh));
    float kv = Kp[src];
    unsigned short kh = f2bf(kv);
    Khi[dst] = kh;
    Klo[dst] = f2bf(kv - bf2f(kh));
}

// ----- scores via split-bf16 MFMA: xy = qh*kh + qh*kl + ql*kh (fp32 acc), then
// exp(-dist/8) epilogue through padded-LDS bounce for coalesced writes + row sums -----
__global__ __launch_bounds__(256) void scores_mfma(const unsigned short* __restrict__ Qhi,
                                                   const unsigned short* __restrict__ Qlo,
                                                   const unsigned short* __restrict__ Khi,
                                                   const unsigned short* __restrict__ Klo,
                                                   const float* __restrict__ qn2,
                                                   const float* __restrict__ kn2,
                                                   float* __restrict__ attn,
                                                   float* __restrict__ part) {
    __shared__ float Cs[128 * 132];                  // also aliased as 4 bf16 staging planes
    __shared__ float qn2s[128], kn2s[128];
    unsigned short* ST = (unsigned short*)Cs;        // planes: p*8192 ushorts (16KB each)
    const int i0 = blockIdx.x * 128;
    const int j0 = blockIdx.y * 128;
    const int bh = blockIdx.z;
    const int tid = threadIdx.x;
    if (tid < 128) {
        qn2s[tid] = qn2[(bh << 11) + i0 + tid];
        kn2s[tid] = kn2[(bh << 11) + j0 + tid];
    }
    // stage 4 planes [128 rows][64 k] bf16, 16B-granule XOR swizzle slot = g ^ (r&7)
    const size_t qbase = ((size_t)(bh << 11) + i0) << 6;
    const size_t kbase = ((size_t)(bh << 11) + j0) << 6;
    const unsigned short* gsrc[4] = {Qhi + qbase, Qlo + qbase, Khi + kbase, Klo + kbase};
#pragma unroll
    for (int p = 0; p < 4; ++p) {
        unsigned short* dstp = ST + p * 8192;
#pragma unroll
        for (int it = 0; it < 4; ++it) {
            const int idx = it * 256 + tid;
            const int r = idx >> 3, g = idx & 7;
            uint4 v = *(const uint4*)(gsrc[p] + r * 64 + g * 8);
            *(uint4*)&dstp[r * 64 + ((g ^ (r & 7)) << 3)] = v;
        }
    }
    __syncthreads();
    const int w = tid >> 6, l = tid & 63;
    const int lr = l & 15, lh = l >> 4;
    const unsigned short* Ah = ST;
    const unsigned short* Al = ST + 8192;
    const unsigned short* Bh = ST + 16384;
    const unsigned short* Bl = ST + 24576;
    f32x4 acc[2][8];
#pragma unroll
    for (int i = 0; i < 2; ++i)
#pragma unroll
        for (int j = 0; j < 8; ++j) acc[i][j] = (f32x4){0.f, 0.f, 0.f, 0.f};
#pragma unroll
    for (int ks = 0; ks < 2; ++ks) {
        const int kb = ks * 4 + lh;
        bf16x8 ah[2], al[2];
#pragma unroll
        for (int fm = 0; fm < 2; ++fm) {
            const int row = w * 32 + fm * 16 + lr;
            const int off = row * 64 + ((kb ^ (row & 7)) << 3);
            ah[fm] = *(const bf16x8*)&Ah[off];
            al[fm] = *(const bf16x8*)&Al[off];
        }
#pragma unroll
        for (int fn = 0; fn < 8; ++fn) {
            const int col = fn * 16 + lr;
            const int boff = col * 64 + ((kb ^ (col & 7)) << 3);
            bf16x8 bh8 = *(const bf16x8*)&Bh[boff];
            bf16x8 bl8 = *(const bf16x8*)&Bl[boff];
#pragma unroll
            for (int fm = 0; fm < 2; ++fm) {
                acc[fm][fn] = __builtin_amdgcn_mfma_f32_16x16x32_bf16(ah[fm], bh8, acc[fm][fn], 0, 0, 0);
                acc[fm][fn] = __builtin_amdgcn_mfma_f32_16x16x32_bf16(al[fm], bh8, acc[fm][fn], 0, 0, 0);
                acc[fm][fn] = __builtin_amdgcn_mfma_f32_16x16x32_bf16(ah[fm], bl8, acc[fm][fn], 0, 0, 0);
            }
        }
    }
    __syncthreads();   // done reading staging planes; reuse LDS as Cs
    // C/D layout (m89-verified): col = lane&15, row = (lane>>4)*4 + reg
#pragma unroll
    for (int fm = 0; fm < 2; ++fm)
#pragma unroll
        for (int fn = 0; fn < 8; ++fn)
#pragma unroll
            for (int r = 0; r < 4; ++r) {
                const int row = w * 32 + fm * 16 + lh * 4 + r;
                const int col = fn * 16 + lr;
                Cs[row * 132 + col] = acc[fm][fn][r];
            }
    __syncthreads();
    // epilogue: thread = (row, half); 64 scores each; coalesced float4 attn writes
    const int erow = tid >> 1;
    const int ecol0 = (tid & 1) * 64;
    const float x2 = qn2s[erow];
    float rs = 0.f;
    float* orow = attn + ((size_t)(bh << 11) + i0 + erow) * kS + j0 + ecol0;
#pragma unroll 4
    for (int i4 = 0; i4 < 16; ++i4) {
        float4 cv  = *(const float4*)&Cs[erow * 132 + ecol0 + i4 * 4];
        float4 y2v = *(const float4*)&kn2s[ecol0 + i4 * 4];
        float xys[4] = {cv.x, cv.y, cv.z, cv.w};
        float y2s[4] = {y2v.x, y2v.y, y2v.z, y2v.w};
        float o[4];
#pragma unroll
        for (int j = 0; j < 4; ++j) {
            float xy = xys[j];
            float y2 = y2s[j];
            float A  = 1.f - 2.f * xy + y2;
            float Bc = 1.f - x2;
            float num2 = A * A * x2 + Bc * Bc * y2 - 2.f * A * Bc * xy;
            float den  = fmaxf(1.f - 2.f * xy + x2 * y2, 1e-15f);
            float sn   = __builtin_amdgcn_sqrtf(fmaxf(num2, 0.f));
            float dm   = den - sn;
            dm = fmaxf(dm, (den + sn) * 5e-8f);                // == artanh clip at 1-1e-7
            float rr = (den + sn) * __builtin_amdgcn_rcpf(dm); // (1+t)/(1-t)
            float e = __builtin_amdgcn_exp2f(-0.125f * __builtin_amdgcn_logf(rr));
            o[j] = e;
            rs += e;
        }
        *(float4*)(orow + i4 * 4) = make_float4(o[0], o[1], o[2], o[3]);
    }
    rs += __shfl_xor(rs, 1, 64);
    if (!(tid & 1)) part[((size_t)(bh << 11) + i0 + erow) * 16 + blockIdx.y] = rs;
}

// ------------------- invS1[row] = 1 / sum_j exp-partials -------------------
__global__ __launch_bounds__(256) void finalize_inv(const float* __restrict__ part,
                                                    float* __restrict__ invS1) {
    const int row = blockIdx.x * 256 + threadIdx.x;
    const float4* p = (const float4*)(part + (size_t)row * 16);
    float4 a = p[0], b = p[1], c = p[2], d = p[3];
    float s = ((a.x + a.y) + (a.z + a.w)) + ((b.x + b.y) + (b.z + b.w)) +
              ((c.x + c.y) + (c.z + c.w)) + ((d.x + d.y) + (d.z + d.w));
    invS1[row] = 1.f / s;
}

// ---- pv_mfma: normalize attn (fp32 writeback) + mid partial = w @ LV via bf16 MFMA ----
__global__ __launch_bounds__(256) void pv_mfma(float* __restrict__ attn,
                                               const unsigned short* __restrict__ LVbT,
                                               const float* __restrict__ invS1,
                                               float* __restrict__ mid0,
                                               float* __restrict__ mid1) {
    __shared__ unsigned short Ash[128 * 64];  // [row][k] bf16, swizzled
    __shared__ unsigned short Bsh[64 * 64];   // [col][k] bf16, swizzled
    __shared__ float isv[128];
    const int i0 = blockIdx.x * 128;
    const int bh = blockIdx.y;
    const int kz = blockIdx.z;
    const int tid = threadIdx.x;
    const int w = tid >> 6, l = tid & 63;
    const int lr = l & 15, lh = l >> 4;
    const size_t arow = (size_t)(bh << 11) + i0;
    const size_t lvbase = ((size_t)bh << 17);          // bh*64*2048
    if (tid < 128) isv[tid] = invS1[arow + tid];
    __syncthreads();

    f32x4 acc[2][4];
#pragma unroll
    for (int i = 0; i < 2; ++i)
#pragma unroll
        for (int j = 0; j < 4; ++j) acc[i][j] = (f32x4){0.f, 0.f, 0.f, 0.f};

    for (int c = 0; c < 16; ++c) {
        const int k0 = kz * 1024 + c * 64;
#pragma unroll
        for (int it = 0; it < 8; ++it) {
            const int t = it * 256 + tid;
            const int r = t >> 4;
            const int c4 = (t & 15) * 4;
            float* ap = attn + (arow + r) * kS + k0 + c4;
            float4 av = *(const float4*)ap;
            const float is = isv[r];
            av.x *= is; av.y *= is; av.z *= is; av.w *= is;
            *(float4*)ap = av;                            // final normalized attn (fp32)
            const int slot = (c4 >> 3) ^ (r & 7);
            uint2 pk;
            pk.x = (unsigned)f2bf(av.x) | ((unsigned)f2bf(av.y) << 16);
            pk.y = (unsigned)f2bf(av.z) | ((unsigned)f2bf(av.w) << 16);
            *(uint2*)&Ash[r * 64 + slot * 8 + (c4 & 4)] = pk;
        }
        {
            const int n = tid >> 2;
            const int kk = (tid & 3) * 16;
            const unsigned short* src = LVbT + lvbase + ((size_t)n << 11) + k0 + kk;
            uint4 s0 = *(const uint4*)src;
            uint4 s1 = *(const uint4*)(src + 8);
            const int kb = kk >> 3;
            *(uint4*)&Bsh[n * 64 + ((kb + 0) ^ (n & 7)) * 8] = s0;
            *(uint4*)&Bsh[n * 64 + ((kb + 1) ^ (n & 7)) * 8] = s1;
        }
        __syncthreads();
        const int wbase = w * 32;
#pragma unroll
        for (int ks = 0; ks < 2; ++ks) {
            const int kbase = ks * 4 + lh;
            bf16x8 afr[2], bfr[4];
#pragma unroll
            for (int fm = 0; fm < 2; ++fm) {
                const int row = wbase + fm * 16 + lr;
                afr[fm] = *(const bf16x8*)&Ash[row * 64 + (kbase ^ (row & 7)) * 8];
            }
#pragma unroll
            for (int fn = 0; fn < 4; ++fn) {
                const int col = fn * 16 + lr;
                bfr[fn] = *(const bf16x8*)&Bsh[col * 64 + (kbase ^ (col & 7)) * 8];
            }
#pragma unroll
            for (int fm = 0; fm < 2; ++fm)
#pragma unroll
                for (int fn = 0; fn < 4; ++fn)
                    acc[fm][fn] = __builtin_amdgcn_mfma_f32_16x16x32_bf16(
                        afr[fm], bfr[fn], acc[fm][fn], 0, 0, 0);
        }
        __syncthreads();
    }
    float* mp = kz ? mid1 : mid0;
#pragma unroll
    for (int fm = 0; fm < 2; ++fm)
#pragma unroll
        for (int fn = 0; fn < 4; ++fn)
#pragma unroll
            for (int r = 0; r < 4; ++r) {
                const int row = (w * 32) + fm * 16 + lh * 4 + r;
                const int col = fn * 16 + lr;
                mp[(arow + row) * kDK + col] = acc[fm][fn][r];
            }
}

// ------------- expmap0 (sum of 2 mid partials) + regather heads to (B,S,D) -------------
__global__ __launch_bounds__(256) void expmap_gather(const float* __restrict__ mid0,
                                                     const float* __restrict__ mid1,
                                                     float* __restrict__ outcat) {
    const int gid  = blockIdx.x * 4 + (threadIdx.x >> 6);
    const int lane = threadIdx.x & 63;
    const int bh = gid >> 11, s = gid & 2047;
    const int b = bh >> 3, h = bh & 7;
    const size_t idx = (size_t)gid * kDK + lane;
    float u = mid0[idx] + mid1[idx];
    float sq = wave_sum64(u * u);
    float un = sqrtf(fmaxf(sq, 1e-15f));
    float coef = tanhf(un) / un;
    outcat[(size_t)(b * kS + s) * kD + h * kDK + lane] = u * coef;
}

} // namespace

extern "C" void kernel_launch(void* const* d_in, const int* in_sizes, int n_in,
                              void* d_out, int out_size, void* d_ws, size_t ws_size,
                              hipStream_t stream) {
    const float* q  = (const float*)d_in[0];
    const float* k  = (const float*)d_in[1];
    const float* v  = (const float*)d_in[2];
    const float* Wq = (const float*)d_in[3];
    const float* bq = (const float*)d_in[4];
    const float* Wk = (const float*)d_in[5];
    const float* bk = (const float*)d_in[6];
    const float* Wv = (const float*)d_in[7];
    const float* bv = (const float*)d_in[8];
    const float* Wo = (const float*)d_in[9];
    const float* bo = (const float*)d_in[10];

    float* out  = (float*)d_out;
    float* attn = out + (size_t)kM * kD;   // out (2M floats), then attn (64M floats)

    constexpr size_t NBUF = (size_t)kM * kD; // 2,097,152 floats (8 MB)
    float* ws  = (float*)d_ws;
    float* A0  = ws;              // Qp  -> later mid partial 0
    float* A1  = ws + NBUF;       // Kp  -> later outcat
    float* A2  = ws + 2 * NBUF;   // Vp  -> Qhi/Qlo bf16 -> mx for final gemm
    float* A3  = ws + 3 * NBUF;   // mx scratch -> LVbT (4MB) + part (2MB) + invS1
    float* qn2 = ws + 4 * NBUF;
    float* kn2 = qn2 + (size_t)kBH * kS;

    constexpr size_t HP = (size_t)kBH * kS * kDK;   // 2,097,152 ushorts = 4 MB per plane
    unsigned short* Qhi = (unsigned short*)A2;
    unsigned short* Qlo = Qhi + HP;
    unsigned short* Khi = (unsigned short*)out;     // out region free until pv writes mid1
    unsigned short* Klo = Khi + HP;
    unsigned short* LVbT = (unsigned short*)A3;     // [bh][64][2048] bf16 (4 MB)
    float* part  = A3 + (1 << 20);                  // after LVbT
    float* invS1 = part + (size_t)kBH * kS * 16;
    float* mid0  = A0;                              // Qp dead after split_qk
    float* mid1  = out;                             // Khi/Klo dead after scores

    dim3 gg(kM / 64, kD / 64);

    gemm_xwt<<<gg, 256, 0, stream>>>(q, Wq, A3);
    rowops<<<kM, 256, 0, stream>>>(q, A3, bq, A0);
    gemm_xwt<<<gg, 256, 0, stream>>>(k, Wk, A3);
    rowops<<<kM, 256, 0, stream>>>(k, A3, bk, A1);
    gemm_xwt<<<gg, 256, 0, stream>>>(v, Wv, A3);
    rowops<<<kM, 256, 0, stream>>>(v, A3, bv, A2);

    prep2<<<kBH * 32, 256, 0, stream>>>(A0, A1, A2, qn2, kn2, LVbT);

    split_qk<<<(kBH * kS) / 4, 256, 0, stream>>>(A0, A1, Qhi, Qlo, Khi, Klo);

    dim3 sg(kS / 128, kS / 128, kBH);
    scores_mfma<<<sg, 256, 0, stream>>>(Qhi, Qlo, Khi, Klo, qn2, kn2, attn, part);

    finalize_inv<<<(kBH * kS) / 256, 256, 0, stream>>>(part, invS1);

    dim3 pg(kS / 128, kBH, 2);
    pv_mfma<<<pg, 256, 0, stream>>>(attn, LVbT, invS1, mid0, mid1);

    expmap_gather<<<(kBH * kS) / 4, 256, 0, stream>>>(mid0, mid1, A1);

    gemm_xwt<<<gg, 256, 0, stream>>>(A1, Wo, A2);
    rowops<<<kM, 256, 0, stream>>>(A1, A2, bo, out);
}

// Round 7
// 382.877 us; speedup vs baseline: 2.6485x; 1.2851x over previous
//
#include <hip/hip_runtime.h>
#include <math.h>

namespace {

constexpr int kB  = 2;
constexpr int kS  = 2048;
constexpr int kD  = 512;
constexpr int kH  = 8;
constexpr int kDK = 64;
constexpr int kM  = kB * kS;   // 4096 rows
constexpr int kBH = kB * kH;   // 16

typedef __attribute__((ext_vector_type(8))) short bf16x8;
typedef __attribute__((ext_vector_type(4))) float f32x4;

__device__ __forceinline__ float wave_sum64(float v) {
#pragma unroll
    for (int o = 32; o > 0; o >>= 1) v += __shfl_xor(v, o, 64);
    return v;
}

__device__ __forceinline__ unsigned short f2bf(float f) {
    unsigned u = __float_as_uint(f);
    unsigned r = (u + 0x7FFF + ((u >> 16) & 1)) >> 16;   // round-to-nearest-even
    return (unsigned short)r;
}
__device__ __forceinline__ float bf2f(unsigned short h) {
    return __uint_as_float(((unsigned)h) << 16);
}

#define MAXN_F  ((float)(1.0 - 1e-5))
#define ACLIP_F ((float)(1.0 - 1e-7))

// ---- GEMM via split-bf16 MFMA: Y(4096x512) = X(4096x512) @ W(512x512)^T ----
// xy = xh*wh + xl*wh + xh*wl in fp32 acc (lo*lo ~1e-8, omitted). Split happens
// during LDS staging (fp32 in, 2 bf16 planes in LDS). 64x64 tile, issue-early
// prefetch of chunk c+1 overlaps HBM/L2 latency with the MFMA phase.
__global__ __launch_bounds__(256) void gemm_mfma(const float* __restrict__ X,
                                                 const float* __restrict__ W,
                                                 float* __restrict__ Y) {
    __shared__ unsigned short Ah[64 * 64], Al[64 * 64], Bh[64 * 64], Bl[64 * 64];
    const int m0 = blockIdx.x * 64;
    const int n0 = blockIdx.y * 64;
    const int tid = threadIdx.x;
    const int w = tid >> 6, l = tid & 63;
    const int lr = l & 15, lh = l >> 4;
    const int sr = tid >> 2;          // staging row 0..63
    const int sk = (tid & 3) * 16;    // staging k base (16 elems/thread)
    float4 xr[4], wr[4];
#pragma unroll
    for (int i = 0; i < 4; ++i) {
        xr[i] = *(const float4*)(X + (size_t)(m0 + sr) * 512 + sk + i * 4);
        wr[i] = *(const float4*)(W + (size_t)(n0 + sr) * 512 + sk + i * 4);
    }
    f32x4 acc[4];
#pragma unroll
    for (int j = 0; j < 4; ++j) acc[j] = (f32x4){0.f, 0.f, 0.f, 0.f};

    for (int c = 0; c < 8; ++c) {
        if (c) __syncthreads();       // previous MFMA done reading LDS
        // split + pack + swizzled LDS write (granules g = sk/8, sk/8+1)
        {
            unsigned hx[8], lx[8], hw_[8], lw_[8];
#pragma unroll
            for (int t = 0; t < 8; ++t) {
                float e0 = ((const float*)&xr[t >> 1])[(t & 1) * 2 + 0];
                float e1 = ((const float*)&xr[t >> 1])[(t & 1) * 2 + 1];
                unsigned short h0 = f2bf(e0), h1 = f2bf(e1);
                hx[t] = (unsigned)h0 | ((unsigned)h1 << 16);
                lx[t] = (unsigned)f2bf(e0 - bf2f(h0)) | ((unsigned)f2bf(e1 - bf2f(h1)) << 16);
                float f0 = ((const float*)&wr[t >> 1])[(t & 1) * 2 + 0];
                float f1 = ((const float*)&wr[t >> 1])[(t & 1) * 2 + 1];
                unsigned short g0 = f2bf(f0), g1 = f2bf(f1);
                hw_[t] = (unsigned)g0 | ((unsigned)g1 << 16);
                lw_[t] = (unsigned)f2bf(f0 - bf2f(g0)) | ((unsigned)f2bf(f1 - bf2f(g1)) << 16);
            }
            const int ga = (sk >> 3) ^ (sr & 7);
            const int gb = ((sk >> 3) + 1) ^ (sr & 7);
            *(uint4*)&Ah[sr * 64 + ga * 8] = make_uint4(hx[0], hx[1], hx[2], hx[3]);
            *(uint4*)&Ah[sr * 64 + gb * 8] = make_uint4(hx[4], hx[5], hx[6], hx[7]);
            *(uint4*)&Al[sr * 64 + ga * 8] = make_uint4(lx[0], lx[1], lx[2], lx[3]);
            *(uint4*)&Al[sr * 64 + gb * 8] = make_uint4(lx[4], lx[5], lx[6], lx[7]);
            *(uint4*)&Bh[sr * 64 + ga * 8] = make_uint4(hw_[0], hw_[1], hw_[2], hw_[3]);
            *(uint4*)&Bh[sr * 64 + gb * 8] = make_uint4(hw_[4], hw_[5], hw_[6], hw_[7]);
            *(uint4*)&Bl[sr * 64 + ga * 8] = make_uint4(lw_[0], lw_[1], lw_[2], lw_[3]);
            *(uint4*)&Bl[sr * 64 + gb * 8] = make_uint4(lw_[4], lw_[5], lw_[6], lw_[7]);
        }
        if (c < 7) {
            const int k1 = (c + 1) * 64;
#pragma unroll
            for (int i = 0; i < 4; ++i) {
                xr[i] = *(const float4*)(X + (size_t)(m0 + sr) * 512 + k1 + sk + i * 4);
                wr[i] = *(const float4*)(W + (size_t)(n0 + sr) * 512 + k1 + sk + i * 4);
            }
        }
        __syncthreads();
#pragma unroll
        for (int ks = 0; ks < 2; ++ks) {
            const int kb = ks * 4 + lh;
            const int row = w * 16 + lr;
            const int aoff = row * 64 + ((kb ^ (row & 7)) << 3);
            bf16x8 ah = *(const bf16x8*)&Ah[aoff];
            bf16x8 al = *(const bf16x8*)&Al[aoff];
#pragma unroll
            for (int fn = 0; fn < 4; ++fn) {
                const int col = fn * 16 + lr;
                const int boff = col * 64 + ((kb ^ (col & 7)) << 3);
                bf16x8 bh8 = *(const bf16x8*)&Bh[boff];
                bf16x8 bl8 = *(const bf16x8*)&Bl[boff];
                acc[fn] = __builtin_amdgcn_mfma_f32_16x16x32_bf16(ah, bh8, acc[fn], 0, 0, 0);
                acc[fn] = __builtin_amdgcn_mfma_f32_16x16x32_bf16(al, bh8, acc[fn], 0, 0, 0);
                acc[fn] = __builtin_amdgcn_mfma_f32_16x16x32_bf16(ah, bl8, acc[fn], 0, 0, 0);
            }
        }
    }
    // C/D layout (m89-verified): col = lane&15, row = (lane>>4)*4 + reg
#pragma unroll
    for (int fn = 0; fn < 4; ++fn)
#pragma unroll
        for (int r = 0; r < 4; ++r)
            Y[(size_t)(m0 + w * 16 + lh * 4 + r) * 512 + n0 + fn * 16 + lr] = acc[fn][r];
}

// --------- mobius_linear tail: res=matvec scale; mobius_add(res,b); project ---------
__global__ __launch_bounds__(256) void rowops(const float* __restrict__ X,
                                              const float* __restrict__ MX,
                                              const float* __restrict__ bvec,
                                              float* __restrict__ out) {
    __shared__ float4 red4[4];
    __shared__ float red1[4];
    const int row = blockIdx.x;
    const int tid = threadIdx.x;
    const float2 xv = ((const float2*)(X + (size_t)row * kD))[tid];
    const float2 mv = ((const float2*)(MX + (size_t)row * kD))[tid];
    const float2 bv = ((const float2*)bvec)[tid];
    float sx  = fmaf(xv.x, xv.x, xv.y * xv.y);
    float sm  = fmaf(mv.x, mv.x, mv.y * mv.y);
    float smb = fmaf(mv.x, bv.x, mv.y * bv.y);
    float sb  = fmaf(bv.x, bv.x, bv.y * bv.y);
#pragma unroll
    for (int o = 32; o > 0; o >>= 1) {
        sx  += __shfl_xor(sx, o, 64);
        sm  += __shfl_xor(sm, o, 64);
        smb += __shfl_xor(smb, o, 64);
        sb  += __shfl_xor(sb, o, 64);
    }
    if ((tid & 63) == 0) red4[tid >> 6] = make_float4(sx, sm, smb, sb);
    __syncthreads();
    {
        float4 r0 = red4[0], r1 = red4[1], r2 = red4[2], r3 = red4[3];
        sx  = r0.x + r1.x + r2.x + r3.x;
        sm  = r0.y + r1.y + r2.y + r3.y;
        smb = r0.z + r1.z + r2.z + r3.z;
        sb  = r0.w + r1.w + r2.w + r3.w;
    }
    float xn  = sqrtf(fmaxf(sx, 1e-15f));
    float mxn = sqrtf(fmaxf(sm, 1e-15f));
    float xc  = fminf(xn, ACLIP_F);
    float at  = 0.5f * logf((1.f + xc) / (1.f - xc));       // artanh(xn)
    float sc  = tanhf(mxn / xn * at) / mxn;                 // res = sc * mx
    if (sm == 0.f) sc = 0.f;                                // all(mx==0) branch
    float x2 = sc * sc * sm;
    float xy = sc * smb;
    float y2 = sb;
    float c1 = 1.f + 2.f * xy + y2;
    float c2 = 1.f - x2;
    float den = fmaxf(1.f + 2.f * xy + x2 * y2, 1e-15f);
    float idn = 1.f / den;
    float ux = (c1 * sc * mv.x + c2 * bv.x) * idn;
    float uy = (c1 * sc * mv.y + c2 * bv.y) * idn;
    float su = wave_sum64(fmaf(ux, ux, uy * uy));
    if ((tid & 63) == 0) red1[tid >> 6] = su;
    __syncthreads();
    su = (red1[0] + red1[1]) + (red1[2] + red1[3]);
    float n = sqrtf(fmaxf(su, 1e-15f));
    float f = (n > MAXN_F) ? (MAXN_F / n) : 1.f;
    ((float2*)(out + (size_t)row * kD))[tid] = make_float2(ux * f, uy * f);
}

// ---- prep2: per-head-row |q|^2,|k|^2 + LVbT[bh][n][k] = bf16(logmap0(V_head))^T ----
__global__ __launch_bounds__(256) void prep2(const float* __restrict__ Qp,
                                             const float* __restrict__ Kp,
                                             const float* __restrict__ Vp,
                                             float* __restrict__ qn2,
                                             float* __restrict__ kn2,
                                             unsigned short* __restrict__ LVbT) {
    __shared__ unsigned short T[64][66];   // [n][s_local], 66 -> 2-way banks (free)
    const int bh = blockIdx.x >> 5;
    const int k0 = (blockIdx.x & 31) * 64;
    const int b = bh >> 3, h = bh & 7;
    const int w = threadIdx.x >> 6, l = threadIdx.x & 63;
#pragma unroll 4
    for (int i = 0; i < 16; ++i) {
        const int s = k0 + w * 16 + i;
        const size_t src = (size_t)(b * kS + s) * kD + h * kDK + l;
        float qv = Qp[src], kv = Kp[src], vv = Vp[src];
        float sq = wave_sum64(qv * qv);
        float sk = wave_sum64(kv * kv);
        float sv = wave_sum64(vv * vv);
        if (l == 0) { qn2[(bh << 11) + s] = sq; kn2[(bh << 11) + s] = sk; }
        float yn = sqrtf(fmaxf(sv, 1e-15f));
        float yc = fminf(yn, ACLIP_F);
        float coef = 0.5f * logf((1.f + yc) / (1.f - yc)) / yn;
        T[l][w * 16 + i] = f2bf(vv * coef);
    }
    __syncthreads();
    const int n = threadIdx.x >> 2, kk = (threadIdx.x & 3) * 16;
    const unsigned int* Tr = (const unsigned int*)&T[n][kk];
    unsigned int u0 = Tr[0], u1 = Tr[1], u2 = Tr[2], u3 = Tr[3];
    unsigned int u4 = Tr[4], u5 = Tr[5], u6 = Tr[6], u7 = Tr[7];
    unsigned short* dst = LVbT + (((size_t)(bh * 64 + n)) << 11) + k0 + kk;
    *(uint4*)dst = make_uint4(u0, u1, u2, u3);
    *(uint4*)(dst + 8) = make_uint4(u4, u5, u6, u7);
}

// ---- split_qk: Q,K head-gathered -> hi/lo bf16 planes [bh][s][64] (split-precision) ----
__global__ __launch_bounds__(256) void split_qk(const float* __restrict__ Qp,
                                                const float* __restrict__ Kp,
                                                unsigned short* __restrict__ Qhi,
                                                unsigned short* __restrict__ Qlo,
                                                unsigned short* __restrict__ Khi,
                                                unsigned short* __restrict__ Klo) {
    const int gid  = blockIdx.x * 4 + (threadIdx.x >> 6);
    const int lane = threadIdx.x & 63;
    const int bh = gid >> 11, s = gid & 2047;
    const int b = bh >> 3, h = bh & 7;
    const size_t src = (size_t)(b * kS + s) * kD + h * kDK + lane;
    const size_t dst = ((size_t)gid << 6) + lane;
    float qv = Qp[src];
    unsigned short qh = f2bf(qv);
    Qhi[dst] = qh;
    Qlo[dst] = f2bf(qv - bf2f(qh));
    float kv = Kp[src];
    unsigned short kh = f2bf(kv);
    Khi[dst] = kh;
    Klo[dst] = f2bf(kv - bf2f(kh));
}

// ----- scores via split-bf16 MFMA: xy = qh*kh + qh*kl + ql*kh (fp32 acc), then
// exp(-dist/8) epilogue through padded-LDS bounce for coalesced writes + row sums -----
__global__ __launch_bounds__(256) void scores_mfma(const unsigned short* __restrict__ Qhi,
                                                   const unsigned short* __restrict__ Qlo,
                                                   const unsigned short* __restrict__ Khi,
                                                   const unsigned short* __restrict__ Klo,
                                                   const float* __restrict__ qn2,
                                                   const float* __restrict__ kn2,
                                                   float* __restrict__ attn,
                                                   float* __restrict__ part) {
    __shared__ float Cs[128 * 132];                  // also aliased as 4 bf16 staging planes
    __shared__ float qn2s[128], kn2s[128];
    unsigned short* ST = (unsigned short*)Cs;        // planes: p*8192 ushorts (16KB each)
    const int i0 = blockIdx.x * 128;
    const int j0 = blockIdx.y * 128;
    const int bh = blockIdx.z;
    const int tid = threadIdx.x;
    if (tid < 128) {
        qn2s[tid] = qn2[(bh << 11) + i0 + tid];
        kn2s[tid] = kn2[(bh << 11) + j0 + tid];
    }
    const size_t qbase = ((size_t)(bh << 11) + i0) << 6;
    const size_t kbase = ((size_t)(bh << 11) + j0) << 6;
    const unsigned short* gsrc[4] = {Qhi + qbase, Qlo + qbase, Khi + kbase, Klo + kbase};
#pragma unroll
    for (int p = 0; p < 4; ++p) {
        unsigned short* dstp = ST + p * 8192;
#pragma unroll
        for (int it = 0; it < 4; ++it) {
            const int idx = it * 256 + tid;
            const int r = idx >> 3, g = idx & 7;
            uint4 v = *(const uint4*)(gsrc[p] + r * 64 + g * 8);
            *(uint4*)&dstp[r * 64 + ((g ^ (r & 7)) << 3)] = v;
        }
    }
    __syncthreads();
    const int w = tid >> 6, l = tid & 63;
    const int lr = l & 15, lh = l >> 4;
    const unsigned short* Ah = ST;
    const unsigned short* Al = ST + 8192;
    const unsigned short* Bh = ST + 16384;
    const unsigned short* Bl = ST + 24576;
    f32x4 acc[2][8];
#pragma unroll
    for (int i = 0; i < 2; ++i)
#pragma unroll
        for (int j = 0; j < 8; ++j) acc[i][j] = (f32x4){0.f, 0.f, 0.f, 0.f};
#pragma unroll
    for (int ks = 0; ks < 2; ++ks) {
        const int kb = ks * 4 + lh;
        bf16x8 ah[2], al[2];
#pragma unroll
        for (int fm = 0; fm < 2; ++fm) {
            const int row = w * 32 + fm * 16 + lr;
            const int off = row * 64 + ((kb ^ (row & 7)) << 3);
            ah[fm] = *(const bf16x8*)&Ah[off];
            al[fm] = *(const bf16x8*)&Al[off];
        }
#pragma unroll
        for (int fn = 0; fn < 8; ++fn) {
            const int col = fn * 16 + lr;
            const int boff = col * 64 + ((kb ^ (col & 7)) << 3);
            bf16x8 bh8 = *(const bf16x8*)&Bh[boff];
            bf16x8 bl8 = *(const bf16x8*)&Bl[boff];
#pragma unroll
            for (int fm = 0; fm < 2; ++fm) {
                acc[fm][fn] = __builtin_amdgcn_mfma_f32_16x16x32_bf16(ah[fm], bh8, acc[fm][fn], 0, 0, 0);
                acc[fm][fn] = __builtin_amdgcn_mfma_f32_16x16x32_bf16(al[fm], bh8, acc[fm][fn], 0, 0, 0);
                acc[fm][fn] = __builtin_amdgcn_mfma_f32_16x16x32_bf16(ah[fm], bl8, acc[fm][fn], 0, 0, 0);
            }
        }
    }
    __syncthreads();   // done reading staging planes; reuse LDS as Cs
#pragma unroll
    for (int fm = 0; fm < 2; ++fm)
#pragma unroll
        for (int fn = 0; fn < 8; ++fn)
#pragma unroll
            for (int r = 0; r < 4; ++r) {
                const int row = w * 32 + fm * 16 + lh * 4 + r;
                const int col = fn * 16 + lr;
                Cs[row * 132 + col] = acc[fm][fn][r];
            }
    __syncthreads();
    const int erow = tid >> 1;
    const int ecol0 = (tid & 1) * 64;
    const float x2 = qn2s[erow];
    float rs = 0.f;
    float* orow = attn + ((size_t)(bh << 11) + i0 + erow) * kS + j0 + ecol0;
#pragma unroll 4
    for (int i4 = 0; i4 < 16; ++i4) {
        float4 cv  = *(const float4*)&Cs[erow * 132 + ecol0 + i4 * 4];
        float4 y2v = *(const float4*)&kn2s[ecol0 + i4 * 4];
        float xys[4] = {cv.x, cv.y, cv.z, cv.w};
        float y2s[4] = {y2v.x, y2v.y, y2v.z, y2v.w};
        float o[4];
#pragma unroll
        for (int j = 0; j < 4; ++j) {
            float xy = xys[j];
            float y2 = y2s[j];
            float A  = 1.f - 2.f * xy + y2;
            float Bc = 1.f - x2;
            float num2 = A * A * x2 + Bc * Bc * y2 - 2.f * A * Bc * xy;
            float den  = fmaxf(1.f - 2.f * xy + x2 * y2, 1e-15f);
            float sn   = __builtin_amdgcn_sqrtf(fmaxf(num2, 0.f));
            float dm   = den - sn;
            dm = fmaxf(dm, (den + sn) * 5e-8f);                // == artanh clip at 1-1e-7
            float rr = (den + sn) * __builtin_amdgcn_rcpf(dm); // (1+t)/(1-t)
            float e = __builtin_amdgcn_exp2f(-0.125f * __builtin_amdgcn_logf(rr));
            o[j] = e;
            rs += e;
        }
        *(float4*)(orow + i4 * 4) = make_float4(o[0], o[1], o[2], o[3]);
    }
    rs += __shfl_xor(rs, 1, 64);
    if (!(tid & 1)) part[((size_t)(bh << 11) + i0 + erow) * 16 + blockIdx.y] = rs;
}

// ------------------- invS1[row] = 1 / sum_j exp-partials -------------------
__global__ __launch_bounds__(256) void finalize_inv(const float* __restrict__ part,
                                                    float* __restrict__ invS1) {
    const int row = blockIdx.x * 256 + threadIdx.x;
    const float4* p = (const float4*)(part + (size_t)row * 16);
    float4 a = p[0], b = p[1], c = p[2], d = p[3];
    float s = ((a.x + a.y) + (a.z + a.w)) + ((b.x + b.y) + (b.z + b.w)) +
              ((c.x + c.y) + (c.z + c.w)) + ((d.x + d.y) + (d.z + d.w));
    invS1[row] = 1.f / s;
}

// ---- pv_mfma: normalize attn (fp32 writeback) + mid partial = w @ LV, bf16 MFMA ----
// M=64 tile, K-split 2 -> grid (32,16,2)=1024 blocks. Issue-early prefetch: chunk c+1
// global loads issued after the LDS-write phase, latency hides under MFMA of chunk c.
__global__ __launch_bounds__(256) void pv_mfma(float* __restrict__ attn,
                                               const unsigned short* __restrict__ LVbT,
                                               const float* __restrict__ invS1,
                                               float* __restrict__ mid0,
                                               float* __restrict__ mid1) {
    __shared__ unsigned short Ash[64 * 64];   // [row][k] bf16, swizzled
    __shared__ unsigned short Bsh[64 * 64];   // [col][k] bf16, swizzled
    __shared__ float isv[64];
    const int i0 = blockIdx.x * 64;
    const int bh = blockIdx.y;
    const int kz = blockIdx.z;
    const int tid = threadIdx.x;
    const int w = tid >> 6, l = tid & 63;
    const int lr = l & 15, lh = l >> 4;
    const size_t arow = (size_t)(bh << 11) + i0;
    const size_t lvbase = ((size_t)bh << 17);          // bh*64*2048
    const int sr  = tid >> 4;          // attn stage rows sr+{0,16,32,48}
    const int sc4 = (tid & 15) * 4;    // attn stage col
    const int bn  = tid >> 2;          // LV stage row (n)
    const int bkk = (tid & 3) * 16;    // LV stage k
    if (tid < 64) isv[tid] = invS1[arow + tid];

    float4 a_reg[4];
    uint4  l_reg[2];
    {
        const int k0 = kz * 1024;
#pragma unroll
        for (int q = 0; q < 4; ++q)
            a_reg[q] = *(const float4*)(attn + (arow + sr + q * 16) * kS + k0 + sc4);
        const unsigned short* src = LVbT + lvbase + ((size_t)bn << 11) + k0 + bkk;
        l_reg[0] = *(const uint4*)src;
        l_reg[1] = *(const uint4*)(src + 8);
    }
    __syncthreads();   // isv ready

    f32x4 acc[4];
#pragma unroll
    for (int j = 0; j < 4; ++j) acc[j] = (f32x4){0.f, 0.f, 0.f, 0.f};

    for (int c = 0; c < 16; ++c) {
        const int k0 = kz * 1024 + c * 64;
        if (c) __syncthreads();            // previous MFMA done reading LDS
        // write phase: normalize, fp32 writeback, bf16 pack -> swizzled LDS
#pragma unroll
        for (int q = 0; q < 4; ++q) {
            const int r = sr + q * 16;
            float4 av = a_reg[q];
            const float is = isv[r];
            av.x *= is; av.y *= is; av.z *= is; av.w *= is;
            *(float4*)(attn + (arow + r) * kS + k0 + sc4) = av;   // final normalized attn
            const int slot = (sc4 >> 3) ^ (r & 7);
            uint2 pk;
            pk.x = (unsigned)f2bf(av.x) | ((unsigned)f2bf(av.y) << 16);
            pk.y = (unsigned)f2bf(av.z) | ((unsigned)f2bf(av.w) << 16);
            *(uint2*)&Ash[r * 64 + slot * 8 + (sc4 & 4)] = pk;
        }
        {
            const int kb = bkk >> 3;
            *(uint4*)&Bsh[bn * 64 + (((kb + 0) ^ (bn & 7)) << 3)] = l_reg[0];
            *(uint4*)&Bsh[bn * 64 + (((kb + 1) ^ (bn & 7)) << 3)] = l_reg[1];
        }
        if (c < 15) {                      // issue-early prefetch of chunk c+1
            const int k1 = k0 + 64;
#pragma unroll
            for (int q = 0; q < 4; ++q)
                a_reg[q] = *(const float4*)(attn + (arow + sr + q * 16) * kS + k1 + sc4);
            const unsigned short* src = LVbT + lvbase + ((size_t)bn << 11) + k1 + bkk;
            l_reg[0] = *(const uint4*)src;
            l_reg[1] = *(const uint4*)(src + 8);
        }
        __syncthreads();
        // MFMA: wave w owns rows [w*16, w*16+16)
#pragma unroll
        for (int ks = 0; ks < 2; ++ks) {
            const int kb = ks * 4 + lh;
            const int row = w * 16 + lr;
            bf16x8 afr = *(const bf16x8*)&Ash[row * 64 + ((kb ^ (row & 7)) << 3)];
#pragma unroll
            for (int fn = 0; fn < 4; ++fn) {
                const int col = fn * 16 + lr;
                bf16x8 bfr = *(const bf16x8*)&Bsh[col * 64 + ((kb ^ (col & 7)) << 3)];
                acc[fn] = __builtin_amdgcn_mfma_f32_16x16x32_bf16(afr, bfr, acc[fn], 0, 0, 0);
            }
        }
    }
    float* mp = kz ? mid1 : mid0;
#pragma unroll
    for (int fn = 0; fn < 4; ++fn)
#pragma unroll
        for (int r = 0; r < 4; ++r)
            mp[(arow + w * 16 + lh * 4 + r) * kDK + fn * 16 + lr] = acc[fn][r];
}

// ------------- expmap0 (sum of 2 mid partials) + regather heads to (B,S,D) -------------
__global__ __launch_bounds__(256) void expmap_gather(const float* __restrict__ mid0,
                                                     const float* __restrict__ mid1,
                                                     float* __restrict__ outcat) {
    const int gid  = blockIdx.x * 4 + (threadIdx.x >> 6);
    const int lane = threadIdx.x & 63;
    const int bh = gid >> 11, s = gid & 2047;
    const int b = bh >> 3, h = bh & 7;
    const size_t idx = (size_t)gid * kDK + lane;
    float u = mid0[idx] + mid1[idx];
    float sq = wave_sum64(u * u);
    float un = sqrtf(fmaxf(sq, 1e-15f));
    float coef = tanhf(un) / un;
    outcat[(size_t)(b * kS + s) * kD + h * kDK + lane] = u * coef;
}

} // namespace

extern "C" void kernel_launch(void* const* d_in, const int* in_sizes, int n_in,
                              void* d_out, int out_size, void* d_ws, size_t ws_size,
                              hipStream_t stream) {
    const float* q  = (const float*)d_in[0];
    const float* k  = (const float*)d_in[1];
    const float* v  = (const float*)d_in[2];
    const float* Wq = (const float*)d_in[3];
    const float* bq = (const float*)d_in[4];
    const float* Wk = (const float*)d_in[5];
    const float* bk = (const float*)d_in[6];
    const float* Wv = (const float*)d_in[7];
    const float* bv = (const float*)d_in[8];
    const float* Wo = (const float*)d_in[9];
    const float* bo = (const float*)d_in[10];

    float* out  = (float*)d_out;
    float* attn = out + (size_t)kM * kD;   // out (2M floats), then attn (64M floats)

    constexpr size_t NBUF = (size_t)kM * kD; // 2,097,152 floats (8 MB)
    float* ws  = (float*)d_ws;
    float* A0  = ws;              // Qp  -> later mid partial 0
    float* A1  = ws + NBUF;       // Kp  -> later outcat
    float* A2  = ws + 2 * NBUF;   // Vp  -> Qhi/Qlo bf16 -> mx for final gemm
    float* A3  = ws + 3 * NBUF;   // mx scratch -> LVbT (4MB) + part (2MB) + invS1
    float* qn2 = ws + 4 * NBUF;
    float* kn2 = qn2 + (size_t)kBH * kS;

    constexpr size_t HP = (size_t)kBH * kS * kDK;   // 2,097,152 ushorts = 4 MB per plane
    unsigned short* Qhi = (unsigned short*)A2;
    unsigned short* Qlo = Qhi + HP;
    unsigned short* Khi = (unsigned short*)out;     // out region free until pv writes mid1
    unsigned short* Klo = Khi + HP;
    unsigned short* LVbT = (unsigned short*)A3;     // [bh][64][2048] bf16 (4 MB)
    float* part  = A3 + (1 << 20);                  // after LVbT
    float* invS1 = part + (size_t)kBH * kS * 16;
    float* mid0  = A0;                              // Qp dead after split_qk
    float* mid1  = out;                             // Khi/Klo dead after scores

    dim3 gg(kM / 64, kD / 64);

    gemm_mfma<<<gg, 256, 0, stream>>>(q, Wq, A3);
    rowops<<<kM, 256, 0, stream>>>(q, A3, bq, A0);
    gemm_mfma<<<gg, 256, 0, stream>>>(k, Wk, A3);
    rowops<<<kM, 256, 0, stream>>>(k, A3, bk, A1);
    gemm_mfma<<<gg, 256, 0, stream>>>(v, Wv, A3);
    rowops<<<kM, 256, 0, stream>>>(v, A3, bv, A2);

    prep2<<<kBH * 32, 256, 0, stream>>>(A0, A1, A2, qn2, kn2, LVbT);

    split_qk<<<(kBH * kS) / 4, 256, 0, stream>>>(A0, A1, Qhi, Qlo, Khi, Klo);

    dim3 sg(kS / 128, kS / 128, kBH);
    scores_mfma<<<sg, 256, 0, stream>>>(Qhi, Qlo, Khi, Klo, qn2, kn2, attn, part);

    finalize_inv<<<(kBH * kS) / 256, 256, 0, stream>>>(part, invS1);

    dim3 pg(kS / 64, kBH, 2);
    pv_mfma<<<pg, 256, 0, stream>>>(attn, LVbT, invS1, mid0, mid1);

    expmap_gather<<<(kBH * kS) / 4, 256, 0, stream>>>(mid0, mid1, A1);

    gemm_mfma<<<gg, 256, 0, stream>>>(A1, Wo, A2);
    rowops<<<kM, 256, 0, stream>>>(A1, A2, bo, out);
}

// Round 8
// 303.345 us; speedup vs baseline: 3.3429x; 1.2622x over previous
//
#include <hip/hip_runtime.h>
#include <math.h>

namespace {

constexpr int kB  = 2;
constexpr int kS  = 2048;
constexpr int kD  = 512;
constexpr int kH  = 8;
constexpr int kDK = 64;
constexpr int kM  = kB * kS;   // 4096 rows
constexpr int kBH = kB * kH;   // 16

typedef __attribute__((ext_vector_type(8))) short bf16x8;
typedef __attribute__((ext_vector_type(4))) float f32x4;

__device__ __forceinline__ float wave_sum64(float v) {
#pragma unroll
    for (int o = 32; o > 0; o >>= 1) v += __shfl_xor(v, o, 64);
    return v;
}

__device__ __forceinline__ unsigned short f2bf(float f) {
    unsigned u = __float_as_uint(f);
    unsigned r = (u + 0x7FFF + ((u >> 16) & 1)) >> 16;   // round-to-nearest-even
    return (unsigned short)r;
}
__device__ __forceinline__ float bf2f(unsigned short h) {
    return __uint_as_float(((unsigned)h) << 16);
}

#define MAXN_F  ((float)(1.0 - 1e-5))
#define ACLIP_F ((float)(1.0 - 1e-7))

// ---- GEMM via split-bf16 MFMA: Y(4096x512) = X(4096x512) @ W(512x512)^T ----
__global__ __launch_bounds__(256) void gemm_mfma(const float* __restrict__ X,
                                                 const float* __restrict__ W,
                                                 float* __restrict__ Y) {
    __shared__ unsigned short Ah[64 * 64], Al[64 * 64], Bh[64 * 64], Bl[64 * 64];
    const int m0 = blockIdx.x * 64;
    const int n0 = blockIdx.y * 64;
    const int tid = threadIdx.x;
    const int w = tid >> 6, l = tid & 63;
    const int lr = l & 15, lh = l >> 4;
    const int sr = tid >> 2;          // staging row 0..63
    const int sk = (tid & 3) * 16;    // staging k base (16 elems/thread)
    float4 xr[4], wr[4];
#pragma unroll
    for (int i = 0; i < 4; ++i) {
        xr[i] = *(const float4*)(X + (size_t)(m0 + sr) * 512 + sk + i * 4);
        wr[i] = *(const float4*)(W + (size_t)(n0 + sr) * 512 + sk + i * 4);
    }
    f32x4 acc[4];
#pragma unroll
    for (int j = 0; j < 4; ++j) acc[j] = (f32x4){0.f, 0.f, 0.f, 0.f};

    for (int c = 0; c < 8; ++c) {
        if (c) __syncthreads();       // previous MFMA done reading LDS
        {
            unsigned hx[8], lx[8], hw_[8], lw_[8];
#pragma unroll
            for (int t = 0; t < 8; ++t) {
                float e0 = ((const float*)&xr[t >> 1])[(t & 1) * 2 + 0];
                float e1 = ((const float*)&xr[t >> 1])[(t & 1) * 2 + 1];
                unsigned short h0 = f2bf(e0), h1 = f2bf(e1);
                hx[t] = (unsigned)h0 | ((unsigned)h1 << 16);
                lx[t] = (unsigned)f2bf(e0 - bf2f(h0)) | ((unsigned)f2bf(e1 - bf2f(h1)) << 16);
                float f0 = ((const float*)&wr[t >> 1])[(t & 1) * 2 + 0];
                float f1 = ((const float*)&wr[t >> 1])[(t & 1) * 2 + 1];
                unsigned short g0 = f2bf(f0), g1 = f2bf(f1);
                hw_[t] = (unsigned)g0 | ((unsigned)g1 << 16);
                lw_[t] = (unsigned)f2bf(f0 - bf2f(g0)) | ((unsigned)f2bf(f1 - bf2f(g1)) << 16);
            }
            const int ga = (sk >> 3) ^ (sr & 7);
            const int gb = ((sk >> 3) + 1) ^ (sr & 7);
            *(uint4*)&Ah[sr * 64 + ga * 8] = make_uint4(hx[0], hx[1], hx[2], hx[3]);
            *(uint4*)&Ah[sr * 64 + gb * 8] = make_uint4(hx[4], hx[5], hx[6], hx[7]);
            *(uint4*)&Al[sr * 64 + ga * 8] = make_uint4(lx[0], lx[1], lx[2], lx[3]);
            *(uint4*)&Al[sr * 64 + gb * 8] = make_uint4(lx[4], lx[5], lx[6], lx[7]);
            *(uint4*)&Bh[sr * 64 + ga * 8] = make_uint4(hw_[0], hw_[1], hw_[2], hw_[3]);
            *(uint4*)&Bh[sr * 64 + gb * 8] = make_uint4(hw_[4], hw_[5], hw_[6], hw_[7]);
            *(uint4*)&Bl[sr * 64 + ga * 8] = make_uint4(lw_[0], lw_[1], lw_[2], lw_[3]);
            *(uint4*)&Bl[sr * 64 + gb * 8] = make_uint4(lw_[4], lw_[5], lw_[6], lw_[7]);
        }
        if (c < 7) {
            const int k1 = (c + 1) * 64;
#pragma unroll
            for (int i = 0; i < 4; ++i) {
                xr[i] = *(const float4*)(X + (size_t)(m0 + sr) * 512 + k1 + sk + i * 4);
                wr[i] = *(const float4*)(W + (size_t)(n0 + sr) * 512 + k1 + sk + i * 4);
            }
        }
        __syncthreads();
#pragma unroll
        for (int ks = 0; ks < 2; ++ks) {
            const int kb = ks * 4 + lh;
            const int row = w * 16 + lr;
            const int aoff = row * 64 + ((kb ^ (row & 7)) << 3);
            bf16x8 ah = *(const bf16x8*)&Ah[aoff];
            bf16x8 al = *(const bf16x8*)&Al[aoff];
#pragma unroll
            for (int fn = 0; fn < 4; ++fn) {
                const int col = fn * 16 + lr;
                const int boff = col * 64 + ((kb ^ (col & 7)) << 3);
                bf16x8 bh8 = *(const bf16x8*)&Bh[boff];
                bf16x8 bl8 = *(const bf16x8*)&Bl[boff];
                acc[fn] = __builtin_amdgcn_mfma_f32_16x16x32_bf16(ah, bh8, acc[fn], 0, 0, 0);
                acc[fn] = __builtin_amdgcn_mfma_f32_16x16x32_bf16(al, bh8, acc[fn], 0, 0, 0);
                acc[fn] = __builtin_amdgcn_mfma_f32_16x16x32_bf16(ah, bl8, acc[fn], 0, 0, 0);
            }
        }
    }
#pragma unroll
    for (int fn = 0; fn < 4; ++fn)
#pragma unroll
        for (int r = 0; r < 4; ++r)
            Y[(size_t)(m0 + w * 16 + lh * 4 + r) * 512 + n0 + fn * 16 + lr] = acc[fn][r];
}

// --------- mobius_linear tail: res=matvec scale; mobius_add(res,b); project ---------
__global__ __launch_bounds__(256) void rowops(const float* __restrict__ X,
                                              const float* __restrict__ MX,
                                              const float* __restrict__ bvec,
                                              float* __restrict__ out) {
    __shared__ float4 red4[4];
    __shared__ float red1[4];
    const int row = blockIdx.x;
    const int tid = threadIdx.x;
    const float2 xv = ((const float2*)(X + (size_t)row * kD))[tid];
    const float2 mv = ((const float2*)(MX + (size_t)row * kD))[tid];
    const float2 bv = ((const float2*)bvec)[tid];
    float sx  = fmaf(xv.x, xv.x, xv.y * xv.y);
    float sm  = fmaf(mv.x, mv.x, mv.y * mv.y);
    float smb = fmaf(mv.x, bv.x, mv.y * bv.y);
    float sb  = fmaf(bv.x, bv.x, bv.y * bv.y);
#pragma unroll
    for (int o = 32; o > 0; o >>= 1) {
        sx  += __shfl_xor(sx, o, 64);
        sm  += __shfl_xor(sm, o, 64);
        smb += __shfl_xor(smb, o, 64);
        sb  += __shfl_xor(sb, o, 64);
    }
    if ((tid & 63) == 0) red4[tid >> 6] = make_float4(sx, sm, smb, sb);
    __syncthreads();
    {
        float4 r0 = red4[0], r1 = red4[1], r2 = red4[2], r3 = red4[3];
        sx  = r0.x + r1.x + r2.x + r3.x;
        sm  = r0.y + r1.y + r2.y + r3.y;
        smb = r0.z + r1.z + r2.z + r3.z;
        sb  = r0.w + r1.w + r2.w + r3.w;
    }
    float xn  = sqrtf(fmaxf(sx, 1e-15f));
    float mxn = sqrtf(fmaxf(sm, 1e-15f));
    float xc  = fminf(xn, ACLIP_F);
    float at  = 0.5f * logf((1.f + xc) / (1.f - xc));       // artanh(xn)
    float sc  = tanhf(mxn / xn * at) / mxn;                 // res = sc * mx
    if (sm == 0.f) sc = 0.f;                                // all(mx==0) branch
    float x2 = sc * sc * sm;
    float xy = sc * smb;
    float y2 = sb;
    float c1 = 1.f + 2.f * xy + y2;
    float c2 = 1.f - x2;
    float den = fmaxf(1.f + 2.f * xy + x2 * y2, 1e-15f);
    float idn = 1.f / den;
    float ux = (c1 * sc * mv.x + c2 * bv.x) * idn;
    float uy = (c1 * sc * mv.y + c2 * bv.y) * idn;
    float su = wave_sum64(fmaf(ux, ux, uy * uy));
    if ((tid & 63) == 0) red1[tid >> 6] = su;
    __syncthreads();
    su = (red1[0] + red1[1]) + (red1[2] + red1[3]);
    float n = sqrtf(fmaxf(su, 1e-15f));
    float f = (n > MAXN_F) ? (MAXN_F / n) : 1.f;
    ((float2*)(out + (size_t)row * kD))[tid] = make_float2(ux * f, uy * f);
}

// ---- prep2: per-head-row |q|^2,|k|^2 + LVbT[bh][n][k] = bf16(logmap0(V_head))^T ----
__global__ __launch_bounds__(256) void prep2(const float* __restrict__ Qp,
                                             const float* __restrict__ Kp,
                                             const float* __restrict__ Vp,
                                             float* __restrict__ qn2,
                                             float* __restrict__ kn2,
                                             unsigned short* __restrict__ LVbT) {
    __shared__ unsigned short T[64][66];   // [n][s_local], 66 -> 2-way banks (free)
    const int bh = blockIdx.x >> 5;
    const int k0 = (blockIdx.x & 31) * 64;
    const int b = bh >> 3, h = bh & 7;
    const int w = threadIdx.x >> 6, l = threadIdx.x & 63;
#pragma unroll 4
    for (int i = 0; i < 16; ++i) {
        const int s = k0 + w * 16 + i;
        const size_t src = (size_t)(b * kS + s) * kD + h * kDK + l;
        float qv = Qp[src], kv = Kp[src], vv = Vp[src];
        float sq = wave_sum64(qv * qv);
        float sk = wave_sum64(kv * kv);
        float sv = wave_sum64(vv * vv);
        if (l == 0) { qn2[(bh << 11) + s] = sq; kn2[(bh << 11) + s] = sk; }
        float yn = sqrtf(fmaxf(sv, 1e-15f));
        float yc = fminf(yn, ACLIP_F);
        float coef = 0.5f * logf((1.f + yc) / (1.f - yc)) / yn;
        T[l][w * 16 + i] = f2bf(vv * coef);
    }
    __syncthreads();
    const int n = threadIdx.x >> 2, kk = (threadIdx.x & 3) * 16;
    const unsigned int* Tr = (const unsigned int*)&T[n][kk];
    unsigned int u0 = Tr[0], u1 = Tr[1], u2 = Tr[2], u3 = Tr[3];
    unsigned int u4 = Tr[4], u5 = Tr[5], u6 = Tr[6], u7 = Tr[7];
    unsigned short* dst = LVbT + (((size_t)(bh * 64 + n)) << 11) + k0 + kk;
    *(uint4*)dst = make_uint4(u0, u1, u2, u3);
    *(uint4*)(dst + 8) = make_uint4(u4, u5, u6, u7);
}

// ---- split_qk: Q,K head-gathered -> hi/lo bf16 planes [bh][s][64] (split-precision) ----
__global__ __launch_bounds__(256) void split_qk(const float* __restrict__ Qp,
                                                const float* __restrict__ Kp,
                                                unsigned short* __restrict__ Qhi,
                                                unsigned short* __restrict__ Qlo,
                                                unsigned short* __restrict__ Khi,
                                                unsigned short* __restrict__ Klo) {
    const int gid  = blockIdx.x * 4 + (threadIdx.x >> 6);
    const int lane = threadIdx.x & 63;
    const int bh = gid >> 11, s = gid & 2047;
    const int b = bh >> 3, h = bh & 7;
    const size_t src = (size_t)(b * kS + s) * kD + h * kDK + lane;
    const size_t dst = ((size_t)gid << 6) + lane;
    float qv = Qp[src];
    unsigned short qh = f2bf(qv);
    Qhi[dst] = qh;
    Qlo[dst] = f2bf(qv - bf2f(qh));
    float kv = Kp[src];
    unsigned short kh = f2bf(kv);
    Khi[dst] = kh;
    Klo[dst] = f2bf(kv - bf2f(kh));
}

// ================= fused_attn =================
// One block = (bh, 32 q-rows). Pass A: stream j-tiles (64 cols): split-bf16 QK MFMA ->
// exp epilogue -> rowsum partials + unnormalized PV MFMA acc. Then in-block: invS,
// mid = pvacc*invS, expmap0, outcat write. Pass B: recompute e, write attn = e*invS
// (the ONLY attn traffic: 268 MB written once).
__global__ __launch_bounds__(256) void fused_attn(const unsigned short* __restrict__ Qhi,
                                                  const unsigned short* __restrict__ Qlo,
                                                  const unsigned short* __restrict__ Khi,
                                                  const unsigned short* __restrict__ Klo,
                                                  const unsigned short* __restrict__ LVbT,
                                                  const float* __restrict__ qn2,
                                                  const float* __restrict__ kn2,
                                                  float* __restrict__ attn,
                                                  float* __restrict__ outcat) {
    __shared__ unsigned short KshH[64 * 64], KshL[64 * 64], LVsh[64 * 64], Psh[32 * 64];
    __shared__ float epl[32 * 68];
    __shared__ float kn2s[2048];
    __shared__ float qn2s[32];
    __shared__ float rsL[4][32], nsL[4][32];
    __shared__ float invSL[32], coefL[32];

    // XCD-pair mapping: XCD x works bh {2x, 2x+1} (K/LV set ~1.5 MB fits per-XCD L2)
    const int wgid = blockIdx.x;
    const int x = wgid & 7, bq_ = wgid >> 3;
    const int bh = 2 * x + (bq_ >> 6);
    const int i0 = (bq_ & 63) * 32;
    const int b = bh >> 3, h = bh & 7;
    const int tid = threadIdx.x;
    const int w = tid >> 6, l = tid & 63;
    const int lr = l & 15, lh = l >> 4;
    const int srj = tid >> 2;            // staging row (j or dk) 0..63
    const int skk = (tid & 3) * 16;      // staging k base
    const size_t kvbase = ((size_t)(bh << 11)) << 6;     // K planes base (shorts)
    const size_t lvbase = ((size_t)bh) << 17;            // LVbT base

    // stage kn2 (all 2048 cols) + qn2 (32 rows)
    {
        const float* src = kn2 + (bh << 11) + tid * 8;
        *(float4*)&kn2s[tid * 8]     = *(const float4*)src;
        *(float4*)&kn2s[tid * 8 + 4] = *(const float4*)(src + 4);
        if (tid < 32) qn2s[tid] = qn2[(bh << 11) + i0 + tid];
    }
    // Q fragments (hi/lo), per wave: m-frags 0,1 x k-steps 0,1
    bf16x8 qah[2][2], qal[2][2];
#pragma unroll
    for (int fm = 0; fm < 2; ++fm)
#pragma unroll
        for (int ks = 0; ks < 2; ++ks) {
            const size_t a = ((size_t)(bh << 11) + i0 + fm * 16 + lr) * 64 + (ks * 4 + lh) * 8;
            qah[fm][ks] = *(const bf16x8*)&Qhi[a];
            qal[fm][ks] = *(const bf16x8*)&Qlo[a];
        }

    const int ga = (((skk >> 3) ^ (srj & 7)) << 3);
    const int gb = ((((skk >> 3) + 1) ^ (srj & 7)) << 3);
    const int jc = w * 16 + lr;          // this wave's col (j in QK n-frag / dk in PV)
    uint4 pA0, pA1, pB0, pB1, pC0, pC1;
    // prefetch tile 0
    {
        const unsigned short* kh = Khi + kvbase + (size_t)srj * 64 + skk;
        const unsigned short* kl = Klo + kvbase + (size_t)srj * 64 + skk;
        const unsigned short* lv = LVbT + lvbase + (size_t)srj * 2048 + skk;
        pA0 = *(const uint4*)kh; pA1 = *(const uint4*)(kh + 8);
        pB0 = *(const uint4*)kl; pB1 = *(const uint4*)(kl + 8);
        pC0 = *(const uint4*)lv; pC1 = *(const uint4*)(lv + 8);
    }

    f32x4 pvacc[2];
    pvacc[0] = (f32x4){0.f, 0.f, 0.f, 0.f};
    pvacc[1] = (f32x4){0.f, 0.f, 0.f, 0.f};
    float rsp[2][4] = {};

    // ---------------- pass A ----------------
    for (int t = 0; t < 32; ++t) {
        const int j0 = t * 64;
        if (t) __syncthreads();
        *(uint4*)&KshH[srj * 64 + ga] = pA0; *(uint4*)&KshH[srj * 64 + gb] = pA1;
        *(uint4*)&KshL[srj * 64 + ga] = pB0; *(uint4*)&KshL[srj * 64 + gb] = pB1;
        *(uint4*)&LVsh[srj * 64 + ga] = pC0; *(uint4*)&LVsh[srj * 64 + gb] = pC1;
        if (t < 31) {
            const unsigned short* kh = Khi + kvbase + (size_t)(j0 + 64 + srj) * 64 + skk;
            const unsigned short* kl = Klo + kvbase + (size_t)(j0 + 64 + srj) * 64 + skk;
            const unsigned short* lv = LVbT + lvbase + (size_t)srj * 2048 + j0 + 64 + skk;
            pA0 = *(const uint4*)kh; pA1 = *(const uint4*)(kh + 8);
            pB0 = *(const uint4*)kl; pB1 = *(const uint4*)(kl + 8);
            pC0 = *(const uint4*)lv; pC1 = *(const uint4*)(lv + 8);
        }
        __syncthreads();
        // QK^T (split-bf16, 3 MFMA per frag pair)
        f32x4 sacc[2];
        sacc[0] = (f32x4){0.f, 0.f, 0.f, 0.f};
        sacc[1] = (f32x4){0.f, 0.f, 0.f, 0.f};
#pragma unroll
        for (int ks = 0; ks < 2; ++ks) {
            const int kb = ks * 4 + lh;
            const int boff = jc * 64 + ((kb ^ (jc & 7)) << 3);
            bf16x8 bh8 = *(const bf16x8*)&KshH[boff];
            bf16x8 bl8 = *(const bf16x8*)&KshL[boff];
#pragma unroll
            for (int fm = 0; fm < 2; ++fm) {
                sacc[fm] = __builtin_amdgcn_mfma_f32_16x16x32_bf16(qah[fm][ks], bh8, sacc[fm], 0, 0, 0);
                sacc[fm] = __builtin_amdgcn_mfma_f32_16x16x32_bf16(qal[fm][ks], bh8, sacc[fm], 0, 0, 0);
                sacc[fm] = __builtin_amdgcn_mfma_f32_16x16x32_bf16(qah[fm][ks], bl8, sacc[fm], 0, 0, 0);
            }
        }
        // epilogue: e = exp(-dist/8); rowsum partial; P -> LDS (bf16, swizzled)
        const float y2 = kn2s[j0 + jc];
        const int pg = jc >> 3, pw = jc & 7;
#pragma unroll
        for (int fm = 0; fm < 2; ++fm)
#pragma unroll
            for (int r = 0; r < 4; ++r) {
                const int row = fm * 16 + lh * 4 + r;
                float xy = sacc[fm][r];
                float x2 = qn2s[row];
                float A_ = 1.f - 2.f * xy + y2;
                float Bc = 1.f - x2;
                float num2 = A_ * A_ * x2 + Bc * Bc * y2 - 2.f * A_ * Bc * xy;
                float den  = fmaxf(1.f - 2.f * xy + x2 * y2, 1e-15f);
                float sn   = __builtin_amdgcn_sqrtf(fmaxf(num2, 0.f));
                float dm   = den - sn;
                dm = fmaxf(dm, (den + sn) * 5e-8f);
                float rr = (den + sn) * __builtin_amdgcn_rcpf(dm);
                float e = __builtin_amdgcn_exp2f(-0.125f * __builtin_amdgcn_logf(rr));
                rsp[fm][r] += e;
                Psh[row * 64 + ((pg ^ (row & 7)) << 3) + pw] = f2bf(e);
            }
        __syncthreads();
        // PV: mid[32][64] += P[32][64j] @ LV[64j][64dk]  (wave w -> dk n-frag w)
#pragma unroll
        for (int ks = 0; ks < 2; ++ks) {
            const int kb = ks * 4 + lh;
            bf16x8 bv8 = *(const bf16x8*)&LVsh[jc * 64 + ((kb ^ (jc & 7)) << 3)];
#pragma unroll
            for (int fm = 0; fm < 2; ++fm) {
                const int prow = fm * 16 + lr;
                bf16x8 pa = *(const bf16x8*)&Psh[prow * 64 + ((kb ^ (prow & 7)) << 3)];
                pvacc[fm] = __builtin_amdgcn_mfma_f32_16x16x32_bf16(pa, bv8, pvacc[fm], 0, 0, 0);
            }
        }
    }
    __syncthreads();
    // rowsums -> invS
#pragma unroll
    for (int fm = 0; fm < 2; ++fm)
#pragma unroll
        for (int r = 0; r < 4; ++r) {
            float v = rsp[fm][r];
            v += __shfl_xor(v, 1, 64); v += __shfl_xor(v, 2, 64);
            v += __shfl_xor(v, 4, 64); v += __shfl_xor(v, 8, 64);
            rsp[fm][r] = v;
        }
    if (lr == 0) {
#pragma unroll
        for (int fm = 0; fm < 2; ++fm)
#pragma unroll
            for (int r = 0; r < 4; ++r) rsL[w][fm * 16 + lh * 4 + r] = rsp[fm][r];
    }
    __syncthreads();
    if (tid < 32) invSL[tid] = 1.f / (rsL[0][tid] + rsL[1][tid] + rsL[2][tid] + rsL[3][tid]);
    __syncthreads();
    // mid = pvacc * invS; expmap0; outcat
    float mval[2][4];
#pragma unroll
    for (int fm = 0; fm < 2; ++fm)
#pragma unroll
        for (int r = 0; r < 4; ++r) {
            const int row = fm * 16 + lh * 4 + r;
            float m = pvacc[fm][r] * invSL[row];
            mval[fm][r] = m;
            float ns = m * m;
            ns += __shfl_xor(ns, 1, 64); ns += __shfl_xor(ns, 2, 64);
            ns += __shfl_xor(ns, 4, 64); ns += __shfl_xor(ns, 8, 64);
            if (lr == 0) nsL[w][row] = ns;
        }
    __syncthreads();
    if (tid < 32) {
        float ns = nsL[0][tid] + nsL[1][tid] + nsL[2][tid] + nsL[3][tid];
        float un = sqrtf(fmaxf(ns, 1e-15f));
        coefL[tid] = tanhf(un) / un;
    }
    __syncthreads();
#pragma unroll
    for (int fm = 0; fm < 2; ++fm)
#pragma unroll
        for (int r = 0; r < 4; ++r) {
            const int row = fm * 16 + lh * 4 + r;
            outcat[(size_t)(b * kS + i0 + row) * kD + h * kDK + jc] = mval[fm][r] * coefL[row];
        }

    // ---------------- pass B: recompute e, write normalized attn once ----------------
    {
        const unsigned short* kh = Khi + kvbase + (size_t)srj * 64 + skk;
        const unsigned short* kl = Klo + kvbase + (size_t)srj * 64 + skk;
        pA0 = *(const uint4*)kh; pA1 = *(const uint4*)(kh + 8);
        pB0 = *(const uint4*)kl; pB1 = *(const uint4*)(kl + 8);
    }
    for (int t = 0; t < 32; ++t) {
        const int j0 = t * 64;
        __syncthreads();
        *(uint4*)&KshH[srj * 64 + ga] = pA0; *(uint4*)&KshH[srj * 64 + gb] = pA1;
        *(uint4*)&KshL[srj * 64 + ga] = pB0; *(uint4*)&KshL[srj * 64 + gb] = pB1;
        if (t < 31) {
            const unsigned short* kh = Khi + kvbase + (size_t)(j0 + 64 + srj) * 64 + skk;
            const unsigned short* kl = Klo + kvbase + (size_t)(j0 + 64 + srj) * 64 + skk;
            pA0 = *(const uint4*)kh; pA1 = *(const uint4*)(kh + 8);
            pB0 = *(const uint4*)kl; pB1 = *(const uint4*)(kl + 8);
        }
        __syncthreads();
        f32x4 sacc[2];
        sacc[0] = (f32x4){0.f, 0.f, 0.f, 0.f};
        sacc[1] = (f32x4){0.f, 0.f, 0.f, 0.f};
#pragma unroll
        for (int ks = 0; ks < 2; ++ks) {
            const int kb = ks * 4 + lh;
            const int boff = jc * 64 + ((kb ^ (jc & 7)) << 3);
            bf16x8 bh8 = *(const bf16x8*)&KshH[boff];
            bf16x8 bl8 = *(const bf16x8*)&KshL[boff];
#pragma unroll
            for (int fm = 0; fm < 2; ++fm) {
                sacc[fm] = __builtin_amdgcn_mfma_f32_16x16x32_bf16(qah[fm][ks], bh8, sacc[fm], 0, 0, 0);
                sacc[fm] = __builtin_amdgcn_mfma_f32_16x16x32_bf16(qal[fm][ks], bh8, sacc[fm], 0, 0, 0);
                sacc[fm] = __builtin_amdgcn_mfma_f32_16x16x32_bf16(qah[fm][ks], bl8, sacc[fm], 0, 0, 0);
            }
        }
        const float y2 = kn2s[j0 + jc];
#pragma unroll
        for (int fm = 0; fm < 2; ++fm)
#pragma unroll
            for (int r = 0; r < 4; ++r) {
                const int row = fm * 16 + lh * 4 + r;
                float xy = sacc[fm][r];
                float x2 = qn2s[row];
                float A_ = 1.f - 2.f * xy + y2;
                float Bc = 1.f - x2;
                float num2 = A_ * A_ * x2 + Bc * Bc * y2 - 2.f * A_ * Bc * xy;
                float den  = fmaxf(1.f - 2.f * xy + x2 * y2, 1e-15f);
                float sn   = __builtin_amdgcn_sqrtf(fmaxf(num2, 0.f));
                float dm   = den - sn;
                dm = fmaxf(dm, (den + sn) * 5e-8f);
                float rr = (den + sn) * __builtin_amdgcn_rcpf(dm);
                float e = __builtin_amdgcn_exp2f(-0.125f * __builtin_amdgcn_logf(rr));
                epl[row * 68 + jc] = e * invSL[row];
            }
        __syncthreads();
        // coalesced attn write: 8 threads/row, 8 floats each
        const int row = tid >> 3, c8 = (tid & 7) * 8;
        float4 v0 = *(const float4*)&epl[row * 68 + c8];
        float4 v1 = *(const float4*)&epl[row * 68 + c8 + 4];
        float* dst = attn + ((size_t)(bh << 11) + i0 + row) * kS + j0 + c8;
        *(float4*)dst = v0;
        *(float4*)(dst + 4) = v1;
    }
}

} // namespace

extern "C" void kernel_launch(void* const* d_in, const int* in_sizes, int n_in,
                              void* d_out, int out_size, void* d_ws, size_t ws_size,
                              hipStream_t stream) {
    const float* q  = (const float*)d_in[0];
    const float* k  = (const float*)d_in[1];
    const float* v  = (const float*)d_in[2];
    const float* Wq = (const float*)d_in[3];
    const float* bq = (const float*)d_in[4];
    const float* Wk = (const float*)d_in[5];
    const float* bk = (const float*)d_in[6];
    const float* Wv = (const float*)d_in[7];
    const float* bv = (const float*)d_in[8];
    const float* Wo = (const float*)d_in[9];
    const float* bo = (const float*)d_in[10];

    float* out  = (float*)d_out;
    float* attn = out + (size_t)kM * kD;   // out (2M floats), then attn (64M floats)

    constexpr size_t NBUF = (size_t)kM * kD; // 2,097,152 floats (8 MB)
    float* ws  = (float*)d_ws;
    float* A0  = ws;              // Qp
    float* A1  = ws + NBUF;       // Kp -> later outcat
    float* A2  = ws + 2 * NBUF;   // Vp -> Qhi/Qlo bf16 -> mx for final gemm
    float* A3  = ws + 3 * NBUF;   // mx scratch -> LVbT (4MB)
    float* qn2 = ws + 4 * NBUF;
    float* kn2 = qn2 + (size_t)kBH * kS;

    constexpr size_t HP = (size_t)kBH * kS * kDK;   // 2,097,152 ushorts = 4 MB per plane
    unsigned short* Qhi = (unsigned short*)A2;
    unsigned short* Qlo = Qhi + HP;
    unsigned short* Khi = (unsigned short*)out;     // out region free until final rowops
    unsigned short* Klo = Khi + HP;
    unsigned short* LVbT = (unsigned short*)A3;     // [bh][64][2048] bf16 (4 MB)

    dim3 gg(kM / 64, kD / 64);

    gemm_mfma<<<gg, 256, 0, stream>>>(q, Wq, A3);
    rowops<<<kM, 256, 0, stream>>>(q, A3, bq, A0);
    gemm_mfma<<<gg, 256, 0, stream>>>(k, Wk, A3);
    rowops<<<kM, 256, 0, stream>>>(k, A3, bk, A1);
    gemm_mfma<<<gg, 256, 0, stream>>>(v, Wv, A3);
    rowops<<<kM, 256, 0, stream>>>(v, A3, bv, A2);

    prep2<<<kBH * 32, 256, 0, stream>>>(A0, A1, A2, qn2, kn2, LVbT);

    split_qk<<<(kBH * kS) / 4, 256, 0, stream>>>(A0, A1, Qhi, Qlo, Khi, Klo);

    fused_attn<<<kBH * (kS / 32), 256, 0, stream>>>(Qhi, Qlo, Khi, Klo, LVbT,
                                                    qn2, kn2, attn, A1);

    gemm_mfma<<<gg, 256, 0, stream>>>(A1, Wo, A2);
    rowops<<<kM, 256, 0, stream>>>(A1, A2, bo, out);
}